// Round 8
// baseline (826.081 us; speedup 1.0000x reference)
//
#include <hip/hip_runtime.h>
#include <hip/hip_fp16.h>

#define N_NODES 100000
#define IN_DIM 64
#define EMB 128
#define N_EDGES 1600000
#define BN_EPS 1e-5f

#define SCAN_ELEMS (N_NODES + 1)        // 100001
#define S1_EPB 1024
#define S1_BLOCKS ((SCAN_ELEMS + S1_EPB - 1) / S1_EPB)   // 98

// ---- workspace layout (bytes) ----
#define WS_ROWSTART 0
#define WS_GSUM     400128
#define WS_GSUM2    400640
#define WS_CURSOR   401152
#define WS_BSUM     801280
#define WS_PAIRS    801792
#define WS_X16      13601792                 // pairs + 12.8 MB
#define WS_NEED_F16 26401792ULL              // x16 + 12.8 MB
#define WS_ZERO_BYTES 401152

// ---------------- 1) histogram of dst (4 edges/thread) ----------------
__global__ __launch_bounds__(256) void hist_kernel(
    const int* __restrict__ ei, int* __restrict__ rowstart)
{
    int e0 = (blockIdx.x * 256 + threadIdx.x) * 4;
    if (e0 >= N_EDGES) return;
    int4 d4 = *(const int4*)(ei + N_EDGES + e0);
    atomicAdd(&rowstart[1 + d4.x], 1);
    atomicAdd(&rowstart[1 + d4.y], 1);
    atomicAdd(&rowstart[1 + d4.z], 1);
    atomicAdd(&rowstart[1 + d4.w], 1);
}

// ---------------- 1b) x -> fp16 sidecar ----------------
__global__ __launch_bounds__(256) void cvt_kernel(
    const float4* __restrict__ x4, uint2* __restrict__ x16)
{
    int i = blockIdx.x * 256 + threadIdx.x;   // 1.6M threads, 4 floats each
    if (i >= N_NODES * IN_DIM / 4) return;
    float4 v = x4[i];
    __half2 lo = __floats2half2_rn(v.x, v.y);
    __half2 hi = __floats2half2_rn(v.z, v.w);
    uint2 u;
    u.x = *(unsigned int*)&lo;
    u.y = *(unsigned int*)&hi;
    x16[i] = u;
}

// ---------------- 2a) per-block reduce of counts ----------------
__global__ __launch_bounds__(256) void scan1_kernel(
    const int* __restrict__ rowstart, int* __restrict__ bsum)
{
    __shared__ int red[256];
    const int t = threadIdx.x;
    const int base = blockIdx.x * S1_EPB + t * 4;
    int s = 0;
    #pragma unroll
    for (int k = 0; k < 4; ++k) {
        int idx = base + k;
        if (idx < SCAN_ELEMS) s += rowstart[idx];
    }
    red[t] = s;
    __syncthreads();
    for (int off = 128; off > 0; off >>= 1) {
        if (t < off) red[t] += red[t + off];
        __syncthreads();
    }
    if (t == 0) bsum[blockIdx.x] = red[0];
}

// ---------------- 2b) exclusive scan of block sums ----------------
__global__ __launch_bounds__(128) void scan2_kernel(int* __restrict__ bsum)
{
    __shared__ int buf[128];
    const int t = threadIdx.x;
    buf[t] = (t < S1_BLOCKS) ? bsum[t] : 0;
    __syncthreads();
    for (int off = 1; off < 128; off <<= 1) {
        int v = (t >= off) ? buf[t - off] : 0;
        __syncthreads();
        buf[t] += v;
        __syncthreads();
    }
    if (t < S1_BLOCKS) bsum[t] = (t > 0) ? buf[t - 1] : 0;
}

// ---------------- 2c) block-local inclusive scan + offset ----------------
__global__ __launch_bounds__(256) void scan3_kernel(
    int* __restrict__ rowstart, int* __restrict__ cursor,
    const int* __restrict__ bsum)
{
    __shared__ int tsum[256];
    const int t = threadIdx.x;
    const int base = blockIdx.x * S1_EPB + t * 4;
    int c0 = 0, c1 = 0, c2 = 0, c3 = 0;
    if (base + 0 < SCAN_ELEMS) c0 = rowstart[base + 0];
    if (base + 1 < SCAN_ELEMS) c1 = rowstart[base + 1];
    if (base + 2 < SCAN_ELEMS) c2 = rowstart[base + 2];
    if (base + 3 < SCAN_ELEMS) c3 = rowstart[base + 3];
    const int i0 = c0, i1 = i0 + c1, i2 = i1 + c2, i3 = i2 + c3;
    tsum[t] = i3;
    __syncthreads();
    for (int off = 1; off < 256; off <<= 1) {
        int v = (t >= off) ? tsum[t - off] : 0;
        __syncthreads();
        tsum[t] += v;
        __syncthreads();
    }
    const int boff = bsum[blockIdx.x] + tsum[t] - i3;
    const int r0 = boff + i0, r1 = boff + i1, r2 = boff + i2, r3 = boff + i3;
    if (base + 0 < SCAN_ELEMS) rowstart[base + 0] = r0;
    if (base + 1 < SCAN_ELEMS) rowstart[base + 1] = r1;
    if (base + 2 < SCAN_ELEMS) rowstart[base + 2] = r2;
    if (base + 3 < SCAN_ELEMS) rowstart[base + 3] = r3;
    if (base + 0 < N_NODES) cursor[base + 0] = r0;
    if (base + 1 < N_NODES) cursor[base + 1] = r1;
    if (base + 2 < N_NODES) cursor[base + 2] = r2;
    if (base + 3 < N_NODES) cursor[base + 3] = r3;
}

// ---------------- 3) fill (src, w) pairs (4 edges/thread) ----------------
__global__ __launch_bounds__(256) void fill_kernel(
    const int* __restrict__ ei, const float* __restrict__ ew,
    int* __restrict__ cursor, float2* __restrict__ pairs)
{
    int e0 = (blockIdx.x * 256 + threadIdx.x) * 4;
    if (e0 >= N_EDGES) return;
    int4   s4 = *(const int4*)(ei + e0);
    int4   d4 = *(const int4*)(ei + N_EDGES + e0);
    float4 w4 = *(const float4*)(ew + e0);
    int p0 = atomicAdd(&cursor[d4.x], 1);
    int p1 = atomicAdd(&cursor[d4.y], 1);
    int p2 = atomicAdd(&cursor[d4.z], 1);
    int p3 = atomicAdd(&cursor[d4.w], 1);
    pairs[p0] = make_float2(__int_as_float(s4.x), w4.x);
    pairs[p1] = make_float2(__int_as_float(s4.y), w4.y);
    pairs[p2] = make_float2(__int_as_float(s4.z), w4.z);
    pairs[p3] = make_float2(__int_as_float(s4.w), w4.w);
}

// ---------------- 4) fused gather + (agg+x)@W1+b1 + BN partial stats ----------------
// Round-5 structure; W1 staged in LDS as fp16 (16 KB) so block LDS ~21 KB
// -> more resident blocks/CU for latency hiding. GEMV uses f32*(f32)f16 fma_mix.
#define B1_NPW 5   // nodes per wave -> grid = 100000/(4*5) = 5000 blocks
template<bool F16>
__global__ __launch_bounds__(256, 4) void mlp1_kernel(
    const float* __restrict__ x,
    const __half* __restrict__ x16,
    const int* __restrict__ rowstart,
    const float2* __restrict__ pairs,
    const float* __restrict__ W1,   // [64,128] row-major
    const float* __restrict__ b1,
    float* __restrict__ h,          // [N,128]
    float* __restrict__ gsum, float* __restrict__ gsum2)
{
    __shared__ __half w1h[IN_DIM][EMB];    // 16 KB
    __shared__ float rowbuf[4][IN_DIM];    // per-wave row (1 KB)
    __shared__ float red[4][2][EMB];       // per-wave col partials (4 KB)

    const int tid  = threadIdx.x;
    const int lane = tid & 63;
    const int wid  = tid >> 6;
    const int lane64 = lane + 64;

    for (int i = tid; i < IN_DIM * EMB; i += 256)
        w1h[i >> 7][i & 127] = __float2half(W1[i]);
    const float bl0 = b1[lane], bl1 = b1[lane64];
    __syncthreads();   // w1h ready

    float s0 = 0.f, s20 = 0.f, s1 = 0.f, s21 = 0.f;
    const int node0 = (blockIdx.x * 4 + wid) * B1_NPW;

    for (int r = 0; r < B1_NPW; ++r) {
        const int n  = node0 + r;
        const int jb = rowstart[n];
        const int je = rowstart[n + 1];

        float accA = x[(size_t)n * IN_DIM + lane];   // self term fp32, (1+eps)=1
        float accB = 0.f;
        for (int j0 = jb; j0 < je; j0 += 64) {
            const int cnt = min(64, je - j0);
            float2 p = (lane < cnt) ? pairs[j0 + lane] : make_float2(0.f, 0.f);
            int   psrc = __float_as_int(p.x);
            float pw   = p.y;
            const int nch = (cnt + 15) >> 4;
            for (int c = 0; c < nch; ++c) {
                const int base = c * 16;
                #pragma unroll
                for (int t = 0; t < 16; t += 2) {
                    int   sA = __shfl(psrc, base + t);
                    float wA = __shfl(pw,   base + t);
                    int   sB = __shfl(psrc, base + t + 1);
                    float wB = __shfl(pw,   base + t + 1);
                    if (F16) {
                        accA += wA * __half2float(x16[(size_t)sA * IN_DIM + lane]);
                        accB += wB * __half2float(x16[(size_t)sB * IN_DIM + lane]);
                    } else {
                        accA += wA * x[(size_t)sA * IN_DIM + lane];
                        accB += wB * x[(size_t)sB * IN_DIM + lane];
                    }
                }
            }
        }
        rowbuf[wid][lane] = accA + accB;

        float a0 = bl0, a1 = bl1;
        const float4* rb4 = (const float4*)rowbuf[wid];
        #pragma unroll
        for (int kg = 0; kg < 16; ++kg) {
            float4 rv = rb4[kg];
            int k = kg * 4;
            a0 += rv.x * __half2float(w1h[k][lane])
                + rv.y * __half2float(w1h[k+1][lane])
                + rv.z * __half2float(w1h[k+2][lane])
                + rv.w * __half2float(w1h[k+3][lane]);
            a1 += rv.x * __half2float(w1h[k][lane64])
                + rv.y * __half2float(w1h[k+1][lane64])
                + rv.z * __half2float(w1h[k+2][lane64])
                + rv.w * __half2float(w1h[k+3][lane64]);
        }
        h[(size_t)n * EMB + lane]   = a0;
        h[(size_t)n * EMB + lane64] = a1;
        s0 += a0; s20 += a0 * a0;
        s1 += a1; s21 += a1 * a1;
    }

    red[wid][0][lane] = s0;  red[wid][0][lane64] = s1;
    red[wid][1][lane] = s20; red[wid][1][lane64] = s21;
    __syncthreads();
    if (tid < EMB) {
        float t0 = red[0][0][tid] + red[1][0][tid] + red[2][0][tid] + red[3][0][tid];
        float t1 = red[0][1][tid] + red[1][1][tid] + red[2][1][tid] + red[3][1][tid];
        atomicAdd(&gsum[tid],  t0);
        atomicAdd(&gsum2[tid], t1);
    }
}

// ---------------- 5) out = relu(BN(h)) @ W2 + b2 (in-place on h) ----------------
#define E_ROWS 80
__global__ __launch_bounds__(256, 2) void mlp2_kernel(
    float* __restrict__ hio,
    const float* __restrict__ gsum, const float* __restrict__ gsum2,
    const float* __restrict__ gamma, const float* __restrict__ beta,
    const float* __restrict__ W2,   // [128,128] row-major
    const float* __restrict__ b2)
{
    __shared__ float nbuf[8][EMB];    // 4 KB

    const int tid = threadIdx.x;
    const int col = tid & 127;
    const int rh  = tid >> 7;

    float w[EMB];
    #pragma unroll
    for (int k = 0; k < EMB; ++k) w[k] = W2[k * EMB + col];

    const float invN = 1.0f / (float)N_NODES;
    float mean = gsum[col] * invN;
    float var  = gsum2[col] * invN - mean * mean;
    float inv  = rsqrtf(var + BN_EPS);
    float a    = gamma[col] * inv;
    float bb   = beta[col] - mean * a;
    float bj   = b2[col];

    const int row0 = blockIdx.x * E_ROWS;
    for (int it = 0; it < E_ROWS / 8; ++it) {
        const int rbase = row0 + it * 8;
        __syncthreads();
        #pragma unroll
        for (int rr = 0; rr < 4; ++rr) {
            int lr = rh * 4 + rr;
            float hv = hio[(size_t)(rbase + lr) * EMB + col];
            nbuf[lr][col] = fmaxf(hv * a + bb, 0.f);
        }
        __syncthreads();
        #pragma unroll
        for (int rr = 0; rr < 4; ++rr) {
            const int lr = rh * 4 + rr;
            const float4* nb4 = (const float4*)&nbuf[lr][0];
            float acc = bj;
            #pragma unroll
            for (int kg = 0; kg < 32; ++kg) {
                float4 nv = nb4[kg];   // broadcast: all lanes same address
                acc += nv.x * w[kg*4+0] + nv.y * w[kg*4+1]
                     + nv.z * w[kg*4+2] + nv.w * w[kg*4+3];
            }
            hio[(size_t)(rbase + lr) * EMB + col] = acc;
        }
    }
}

extern "C" void kernel_launch(void* const* d_in, const int* in_sizes, int n_in,
                              void* d_out, int out_size, void* d_ws, size_t ws_size,
                              hipStream_t stream)
{
    const float* x     = (const float*)d_in[0];
    const int*   ei    = (const int*)d_in[1];   // int32 [2,E]
    const float* ew    = (const float*)d_in[3];
    const float* W1    = (const float*)d_in[4];
    const float* b1    = (const float*)d_in[5];
    const float* gamma = (const float*)d_in[6];
    const float* beta  = (const float*)d_in[7];
    const float* W2    = (const float*)d_in[8];
    const float* b2    = (const float*)d_in[9];

    char* ws = (char*)d_ws;
    int*    rowstart = (int*)(ws + WS_ROWSTART);
    int*    cursor   = (int*)(ws + WS_CURSOR);
    float*  gsum     = (float*)(ws + WS_GSUM);
    float*  gsum2    = (float*)(ws + WS_GSUM2);
    int*    bsum     = (int*)(ws + WS_BSUM);
    float2* pairs    = (float2*)(ws + WS_PAIRS);
    __half* x16      = (__half*)(ws + WS_X16);
    float*  h        = (float*)d_out;

    const bool use16 = (ws_size >= WS_NEED_F16);

    hipMemsetAsync(d_ws, 0, WS_ZERO_BYTES, stream);

    hist_kernel<<<(N_EDGES / 4 + 255) / 256, 256, 0, stream>>>(ei, rowstart);
    if (use16)
        cvt_kernel<<<(N_NODES * IN_DIM / 4 + 255) / 256, 256, 0, stream>>>(
            (const float4*)x, (uint2*)x16);
    scan1_kernel<<<S1_BLOCKS, 256, 0, stream>>>(rowstart, bsum);
    scan2_kernel<<<1, 128, 0, stream>>>(bsum);
    scan3_kernel<<<S1_BLOCKS, 256, 0, stream>>>(rowstart, cursor, bsum);
    fill_kernel<<<(N_EDGES / 4 + 255) / 256, 256, 0, stream>>>(ei, ew, cursor, pairs);
    if (use16)
        mlp1_kernel<true><<<N_NODES / (4 * B1_NPW), 256, 0, stream>>>(
            x, x16, rowstart, pairs, W1, b1, h, gsum, gsum2);
    else
        mlp1_kernel<false><<<N_NODES / (4 * B1_NPW), 256, 0, stream>>>(
            x, x16, rowstart, pairs, W1, b1, h, gsum, gsum2);
    mlp2_kernel<<<N_NODES / E_ROWS, 256, 0, stream>>>(h, gsum, gsum2, gamma, beta, W2, b2);
}

// Round 9
// 511.082 us; speedup vs baseline: 1.6163x; 1.6163x over previous
//
#include <hip/hip_runtime.h>
#include <hip/hip_fp16.h>

#define N_NODES 100000
#define IN_DIM 64
#define EMB 128
#define N_EDGES 1600000
#define BN_EPS 1e-5f

#define SCAN_ELEMS (N_NODES + 1)        // 100001
#define S1_EPB 1024
#define S1_BLOCKS ((SCAN_ELEMS + S1_EPB - 1) / S1_EPB)   // 98

// ---- workspace layout (bytes) ----
#define WS_ROWSTART 0
#define WS_GSUM     400128
#define WS_GSUM2    400640
#define WS_CURSOR   401152
#define WS_BSUM     801280
#define WS_PAIRS    801792
#define WS_X16      13601792                 // pairs + 12.8 MB
#define WS_NEED_F16 26401792ULL              // x16 + 12.8 MB
#define WS_ZERO_BYTES 401152

// ---------------- 1) histogram of dst (4 edges/thread) ----------------
__global__ __launch_bounds__(256) void hist_kernel(
    const int* __restrict__ ei, int* __restrict__ rowstart)
{
    int e0 = (blockIdx.x * 256 + threadIdx.x) * 4;
    if (e0 >= N_EDGES) return;
    int4 d4 = *(const int4*)(ei + N_EDGES + e0);
    atomicAdd(&rowstart[1 + d4.x], 1);
    atomicAdd(&rowstart[1 + d4.y], 1);
    atomicAdd(&rowstart[1 + d4.z], 1);
    atomicAdd(&rowstart[1 + d4.w], 1);
}

// ---------------- 1b) x -> fp16 sidecar ----------------
__global__ __launch_bounds__(256) void cvt_kernel(
    const float4* __restrict__ x4, uint2* __restrict__ x16)
{
    int i = blockIdx.x * 256 + threadIdx.x;   // 1.6M threads, 4 floats each
    if (i >= N_NODES * IN_DIM / 4) return;
    float4 v = x4[i];
    __half2 lo = __floats2half2_rn(v.x, v.y);
    __half2 hi = __floats2half2_rn(v.z, v.w);
    uint2 u;
    u.x = *(unsigned int*)&lo;
    u.y = *(unsigned int*)&hi;
    x16[i] = u;
}

// ---------------- 2a) per-block reduce of counts ----------------
__global__ __launch_bounds__(256) void scan1_kernel(
    const int* __restrict__ rowstart, int* __restrict__ bsum)
{
    __shared__ int red[256];
    const int t = threadIdx.x;
    const int base = blockIdx.x * S1_EPB + t * 4;
    int s = 0;
    #pragma unroll
    for (int k = 0; k < 4; ++k) {
        int idx = base + k;
        if (idx < SCAN_ELEMS) s += rowstart[idx];
    }
    red[t] = s;
    __syncthreads();
    for (int off = 128; off > 0; off >>= 1) {
        if (t < off) red[t] += red[t + off];
        __syncthreads();
    }
    if (t == 0) bsum[blockIdx.x] = red[0];
}

// ---------------- 2b) exclusive scan of block sums ----------------
__global__ __launch_bounds__(128) void scan2_kernel(int* __restrict__ bsum)
{
    __shared__ int buf[128];
    const int t = threadIdx.x;
    buf[t] = (t < S1_BLOCKS) ? bsum[t] : 0;
    __syncthreads();
    for (int off = 1; off < 128; off <<= 1) {
        int v = (t >= off) ? buf[t - off] : 0;
        __syncthreads();
        buf[t] += v;
        __syncthreads();
    }
    if (t < S1_BLOCKS) bsum[t] = (t > 0) ? buf[t - 1] : 0;
}

// ---------------- 2c) block-local inclusive scan + offset ----------------
__global__ __launch_bounds__(256) void scan3_kernel(
    int* __restrict__ rowstart, int* __restrict__ cursor,
    const int* __restrict__ bsum)
{
    __shared__ int tsum[256];
    const int t = threadIdx.x;
    const int base = blockIdx.x * S1_EPB + t * 4;
    int c0 = 0, c1 = 0, c2 = 0, c3 = 0;
    if (base + 0 < SCAN_ELEMS) c0 = rowstart[base + 0];
    if (base + 1 < SCAN_ELEMS) c1 = rowstart[base + 1];
    if (base + 2 < SCAN_ELEMS) c2 = rowstart[base + 2];
    if (base + 3 < SCAN_ELEMS) c3 = rowstart[base + 3];
    const int i0 = c0, i1 = i0 + c1, i2 = i1 + c2, i3 = i2 + c3;
    tsum[t] = i3;
    __syncthreads();
    for (int off = 1; off < 256; off <<= 1) {
        int v = (t >= off) ? tsum[t - off] : 0;
        __syncthreads();
        tsum[t] += v;
        __syncthreads();
    }
    const int boff = bsum[blockIdx.x] + tsum[t] - i3;
    const int r0 = boff + i0, r1 = boff + i1, r2 = boff + i2, r3 = boff + i3;
    if (base + 0 < SCAN_ELEMS) rowstart[base + 0] = r0;
    if (base + 1 < SCAN_ELEMS) rowstart[base + 1] = r1;
    if (base + 2 < SCAN_ELEMS) rowstart[base + 2] = r2;
    if (base + 3 < SCAN_ELEMS) rowstart[base + 3] = r3;
    if (base + 0 < N_NODES) cursor[base + 0] = r0;
    if (base + 1 < N_NODES) cursor[base + 1] = r1;
    if (base + 2 < N_NODES) cursor[base + 2] = r2;
    if (base + 3 < N_NODES) cursor[base + 3] = r3;
}

// ---------------- 3) fill (src, w) pairs (4 edges/thread) ----------------
__global__ __launch_bounds__(256) void fill_kernel(
    const int* __restrict__ ei, const float* __restrict__ ew,
    int* __restrict__ cursor, float2* __restrict__ pairs)
{
    int e0 = (blockIdx.x * 256 + threadIdx.x) * 4;
    if (e0 >= N_EDGES) return;
    int4   s4 = *(const int4*)(ei + e0);
    int4   d4 = *(const int4*)(ei + N_EDGES + e0);
    float4 w4 = *(const float4*)(ew + e0);
    int p0 = atomicAdd(&cursor[d4.x], 1);
    int p1 = atomicAdd(&cursor[d4.y], 1);
    int p2 = atomicAdd(&cursor[d4.z], 1);
    int p3 = atomicAdd(&cursor[d4.w], 1);
    pairs[p0] = make_float2(__int_as_float(s4.x), w4.x);
    pairs[p1] = make_float2(__int_as_float(s4.y), w4.y);
    pairs[p2] = make_float2(__int_as_float(s4.z), w4.z);
    pairs[p3] = make_float2(__int_as_float(s4.w), w4.w);
}

// ---------------- 4) fused gather + (agg+x)@W1+b1 + BN partial stats ----------------
// Round-5 structure; W1 staged in LDS as fp16 (16 KB, block LDS ~21.5 KB).
// NO min-waves clamp: round 8 showed (256,4) forces VGPR=64 -> massive spills
// (FETCH 99.6->919 MB). Compiler picks ~112 VGPR -> 4 waves/SIMD, LDS allows
// more blocks than round 7's 32 KB staging.
#define B1_NPW 5   // nodes per wave -> grid = 100000/(4*5) = 5000 blocks
template<bool F16>
__global__ __launch_bounds__(256) void mlp1_kernel(
    const float* __restrict__ x,
    const __half* __restrict__ x16,
    const int* __restrict__ rowstart,
    const float2* __restrict__ pairs,
    const float* __restrict__ W1,   // [64,128] row-major
    const float* __restrict__ b1,
    float* __restrict__ h,          // [N,128]
    float* __restrict__ gsum, float* __restrict__ gsum2)
{
    __shared__ __half w1h[IN_DIM][EMB];    // 16 KB
    __shared__ float rowbuf[4][IN_DIM];    // per-wave row (1 KB)
    __shared__ float red[4][2][EMB];       // per-wave col partials (4 KB)

    const int tid  = threadIdx.x;
    const int lane = tid & 63;
    const int wid  = tid >> 6;
    const int lane64 = lane + 64;

    for (int i = tid; i < IN_DIM * EMB; i += 256)
        w1h[i >> 7][i & 127] = __float2half(W1[i]);
    const float bl0 = b1[lane], bl1 = b1[lane64];
    __syncthreads();   // w1h ready

    float s0 = 0.f, s20 = 0.f, s1 = 0.f, s21 = 0.f;
    const int node0 = (blockIdx.x * 4 + wid) * B1_NPW;

    for (int r = 0; r < B1_NPW; ++r) {
        const int n  = node0 + r;
        const int jb = rowstart[n];
        const int je = rowstart[n + 1];

        float accA = x[(size_t)n * IN_DIM + lane];   // self term fp32, (1+eps)=1
        float accB = 0.f;
        for (int j0 = jb; j0 < je; j0 += 64) {
            const int cnt = min(64, je - j0);
            float2 p = (lane < cnt) ? pairs[j0 + lane] : make_float2(0.f, 0.f);
            int   psrc = __float_as_int(p.x);
            float pw   = p.y;
            const int nch = (cnt + 15) >> 4;
            for (int c = 0; c < nch; ++c) {
                const int base = c * 16;
                #pragma unroll
                for (int t = 0; t < 16; t += 2) {
                    int   sA = __shfl(psrc, base + t);
                    float wA = __shfl(pw,   base + t);
                    int   sB = __shfl(psrc, base + t + 1);
                    float wB = __shfl(pw,   base + t + 1);
                    if (F16) {
                        accA += wA * __half2float(x16[(size_t)sA * IN_DIM + lane]);
                        accB += wB * __half2float(x16[(size_t)sB * IN_DIM + lane]);
                    } else {
                        accA += wA * x[(size_t)sA * IN_DIM + lane];
                        accB += wB * x[(size_t)sB * IN_DIM + lane];
                    }
                }
            }
        }
        rowbuf[wid][lane] = accA + accB;

        float a0 = bl0, a1 = bl1;
        const float4* rb4 = (const float4*)rowbuf[wid];
        #pragma unroll
        for (int kg = 0; kg < 16; ++kg) {
            float4 rv = rb4[kg];
            int k = kg * 4;
            a0 += rv.x * __half2float(w1h[k][lane])
                + rv.y * __half2float(w1h[k+1][lane])
                + rv.z * __half2float(w1h[k+2][lane])
                + rv.w * __half2float(w1h[k+3][lane]);
            a1 += rv.x * __half2float(w1h[k][lane64])
                + rv.y * __half2float(w1h[k+1][lane64])
                + rv.z * __half2float(w1h[k+2][lane64])
                + rv.w * __half2float(w1h[k+3][lane64]);
        }
        h[(size_t)n * EMB + lane]   = a0;
        h[(size_t)n * EMB + lane64] = a1;
        s0 += a0; s20 += a0 * a0;
        s1 += a1; s21 += a1 * a1;
    }

    red[wid][0][lane] = s0;  red[wid][0][lane64] = s1;
    red[wid][1][lane] = s20; red[wid][1][lane64] = s21;
    __syncthreads();
    if (tid < EMB) {
        float t0 = red[0][0][tid] + red[1][0][tid] + red[2][0][tid] + red[3][0][tid];
        float t1 = red[0][1][tid] + red[1][1][tid] + red[2][1][tid] + red[3][1][tid];
        atomicAdd(&gsum[tid],  t0);
        atomicAdd(&gsum2[tid], t1);
    }
}

// ---------------- 5) out = relu(BN(h)) @ W2 + b2 (in-place on h) ----------------
#define E_ROWS 80
__global__ __launch_bounds__(256, 2) void mlp2_kernel(
    float* __restrict__ hio,
    const float* __restrict__ gsum, const float* __restrict__ gsum2,
    const float* __restrict__ gamma, const float* __restrict__ beta,
    const float* __restrict__ W2,   // [128,128] row-major
    const float* __restrict__ b2)
{
    __shared__ float nbuf[8][EMB];    // 4 KB

    const int tid = threadIdx.x;
    const int col = tid & 127;
    const int rh  = tid >> 7;

    float w[EMB];
    #pragma unroll
    for (int k = 0; k < EMB; ++k) w[k] = W2[k * EMB + col];

    const float invN = 1.0f / (float)N_NODES;
    float mean = gsum[col] * invN;
    float var  = gsum2[col] * invN - mean * mean;
    float inv  = rsqrtf(var + BN_EPS);
    float a    = gamma[col] * inv;
    float bb   = beta[col] - mean * a;
    float bj   = b2[col];

    const int row0 = blockIdx.x * E_ROWS;
    for (int it = 0; it < E_ROWS / 8; ++it) {
        const int rbase = row0 + it * 8;
        __syncthreads();
        #pragma unroll
        for (int rr = 0; rr < 4; ++rr) {
            int lr = rh * 4 + rr;
            float hv = hio[(size_t)(rbase + lr) * EMB + col];
            nbuf[lr][col] = fmaxf(hv * a + bb, 0.f);
        }
        __syncthreads();
        #pragma unroll
        for (int rr = 0; rr < 4; ++rr) {
            const int lr = rh * 4 + rr;
            const float4* nb4 = (const float4*)&nbuf[lr][0];
            float acc = bj;
            #pragma unroll
            for (int kg = 0; kg < 32; ++kg) {
                float4 nv = nb4[kg];   // broadcast: all lanes same address
                acc += nv.x * w[kg*4+0] + nv.y * w[kg*4+1]
                     + nv.z * w[kg*4+2] + nv.w * w[kg*4+3];
            }
            hio[(size_t)(rbase + lr) * EMB + col] = acc;
        }
    }
}

extern "C" void kernel_launch(void* const* d_in, const int* in_sizes, int n_in,
                              void* d_out, int out_size, void* d_ws, size_t ws_size,
                              hipStream_t stream)
{
    const float* x     = (const float*)d_in[0];
    const int*   ei    = (const int*)d_in[1];   // int32 [2,E]
    const float* ew    = (const float*)d_in[3];
    const float* W1    = (const float*)d_in[4];
    const float* b1    = (const float*)d_in[5];
    const float* gamma = (const float*)d_in[6];
    const float* beta  = (const float*)d_in[7];
    const float* W2    = (const float*)d_in[8];
    const float* b2    = (const float*)d_in[9];

    char* ws = (char*)d_ws;
    int*    rowstart = (int*)(ws + WS_ROWSTART);
    int*    cursor   = (int*)(ws + WS_CURSOR);
    float*  gsum     = (float*)(ws + WS_GSUM);
    float*  gsum2    = (float*)(ws + WS_GSUM2);
    int*    bsum     = (int*)(ws + WS_BSUM);
    float2* pairs    = (float2*)(ws + WS_PAIRS);
    __half* x16      = (__half*)(ws + WS_X16);
    float*  h        = (float*)d_out;

    const bool use16 = (ws_size >= WS_NEED_F16);

    hipMemsetAsync(d_ws, 0, WS_ZERO_BYTES, stream);

    hist_kernel<<<(N_EDGES / 4 + 255) / 256, 256, 0, stream>>>(ei, rowstart);
    if (use16)
        cvt_kernel<<<(N_NODES * IN_DIM / 4 + 255) / 256, 256, 0, stream>>>(
            (const float4*)x, (uint2*)x16);
    scan1_kernel<<<S1_BLOCKS, 256, 0, stream>>>(rowstart, bsum);
    scan2_kernel<<<1, 128, 0, stream>>>(bsum);
    scan3_kernel<<<S1_BLOCKS, 256, 0, stream>>>(rowstart, cursor, bsum);
    fill_kernel<<<(N_EDGES / 4 + 255) / 256, 256, 0, stream>>>(ei, ew, cursor, pairs);
    if (use16)
        mlp1_kernel<true><<<N_NODES / (4 * B1_NPW), 256, 0, stream>>>(
            x, x16, rowstart, pairs, W1, b1, h, gsum, gsum2);
    else
        mlp1_kernel<false><<<N_NODES / (4 * B1_NPW), 256, 0, stream>>>(
            x, x16, rowstart, pairs, W1, b1, h, gsum, gsum2);
    mlp2_kernel<<<N_NODES / E_ROWS, 256, 0, stream>>>(h, gsum, gsum2, gamma, beta, W2, b2);
}

// Round 10
// 448.521 us; speedup vs baseline: 1.8418x; 1.1395x over previous
//
#include <hip/hip_runtime.h>

#define N_NODES 100000
#define IN_DIM 64
#define EMB 128
#define N_EDGES 1600000
#define BN_EPS 1e-5f

#define SCAN_ELEMS (N_NODES + 1)        // 100001
#define S1_EPB 1024
#define S1_BLOCKS ((SCAN_ELEMS + S1_EPB - 1) / S1_EPB)   // 98

// ---- workspace layout (bytes) ----
#define WS_ROWSTART 0
#define WS_GSUM     400128
#define WS_GSUM2    400640
#define WS_CURSOR   401152
#define WS_BSUM     801280
#define WS_PAIRS    801792
#define WS_AGG      13601792                 // pairs + 12.8 MB
#define WS_NEED_SPLIT 39201792ULL            // agg + 25.6 MB
#define WS_ZERO_BYTES 401152

// ---------------- 1) histogram of dst (4 edges/thread) ----------------
__global__ __launch_bounds__(256) void hist_kernel(
    const int* __restrict__ ei, int* __restrict__ rowstart)
{
    int e0 = (blockIdx.x * 256 + threadIdx.x) * 4;
    if (e0 >= N_EDGES) return;
    int4 d4 = *(const int4*)(ei + N_EDGES + e0);
    atomicAdd(&rowstart[1 + d4.x], 1);
    atomicAdd(&rowstart[1 + d4.y], 1);
    atomicAdd(&rowstart[1 + d4.z], 1);
    atomicAdd(&rowstart[1 + d4.w], 1);
}

// ---------------- 2a) per-block reduce of counts ----------------
__global__ __launch_bounds__(256) void scan1_kernel(
    const int* __restrict__ rowstart, int* __restrict__ bsum)
{
    __shared__ int red[256];
    const int t = threadIdx.x;
    const int base = blockIdx.x * S1_EPB + t * 4;
    int s = 0;
    #pragma unroll
    for (int k = 0; k < 4; ++k) {
        int idx = base + k;
        if (idx < SCAN_ELEMS) s += rowstart[idx];
    }
    red[t] = s;
    __syncthreads();
    for (int off = 128; off > 0; off >>= 1) {
        if (t < off) red[t] += red[t + off];
        __syncthreads();
    }
    if (t == 0) bsum[blockIdx.x] = red[0];
}

// ---------------- 2b) exclusive scan of block sums ----------------
__global__ __launch_bounds__(128) void scan2_kernel(int* __restrict__ bsum)
{
    __shared__ int buf[128];
    const int t = threadIdx.x;
    buf[t] = (t < S1_BLOCKS) ? bsum[t] : 0;
    __syncthreads();
    for (int off = 1; off < 128; off <<= 1) {
        int v = (t >= off) ? buf[t - off] : 0;
        __syncthreads();
        buf[t] += v;
        __syncthreads();
    }
    if (t < S1_BLOCKS) bsum[t] = (t > 0) ? buf[t - 1] : 0;
}

// ---------------- 2c) block-local inclusive scan + offset ----------------
__global__ __launch_bounds__(256) void scan3_kernel(
    int* __restrict__ rowstart, int* __restrict__ cursor,
    const int* __restrict__ bsum)
{
    __shared__ int tsum[256];
    const int t = threadIdx.x;
    const int base = blockIdx.x * S1_EPB + t * 4;
    int c0 = 0, c1 = 0, c2 = 0, c3 = 0;
    if (base + 0 < SCAN_ELEMS) c0 = rowstart[base + 0];
    if (base + 1 < SCAN_ELEMS) c1 = rowstart[base + 1];
    if (base + 2 < SCAN_ELEMS) c2 = rowstart[base + 2];
    if (base + 3 < SCAN_ELEMS) c3 = rowstart[base + 3];
    const int i0 = c0, i1 = i0 + c1, i2 = i1 + c2, i3 = i2 + c3;
    tsum[t] = i3;
    __syncthreads();
    for (int off = 1; off < 256; off <<= 1) {
        int v = (t >= off) ? tsum[t - off] : 0;
        __syncthreads();
        tsum[t] += v;
        __syncthreads();
    }
    const int boff = bsum[blockIdx.x] + tsum[t] - i3;
    const int r0 = boff + i0, r1 = boff + i1, r2 = boff + i2, r3 = boff + i3;
    if (base + 0 < SCAN_ELEMS) rowstart[base + 0] = r0;
    if (base + 1 < SCAN_ELEMS) rowstart[base + 1] = r1;
    if (base + 2 < SCAN_ELEMS) rowstart[base + 2] = r2;
    if (base + 3 < SCAN_ELEMS) rowstart[base + 3] = r3;
    if (base + 0 < N_NODES) cursor[base + 0] = r0;
    if (base + 1 < N_NODES) cursor[base + 1] = r1;
    if (base + 2 < N_NODES) cursor[base + 2] = r2;
    if (base + 3 < N_NODES) cursor[base + 3] = r3;
}

// ---------------- 3) fill (src, w) pairs (4 edges/thread) ----------------
__global__ __launch_bounds__(256) void fill_kernel(
    const int* __restrict__ ei, const float* __restrict__ ew,
    int* __restrict__ cursor, float2* __restrict__ pairs)
{
    int e0 = (blockIdx.x * 256 + threadIdx.x) * 4;
    if (e0 >= N_EDGES) return;
    int4   s4 = *(const int4*)(ei + e0);
    int4   d4 = *(const int4*)(ei + N_EDGES + e0);
    float4 w4 = *(const float4*)(ew + e0);
    int p0 = atomicAdd(&cursor[d4.x], 1);
    int p1 = atomicAdd(&cursor[d4.y], 1);
    int p2 = atomicAdd(&cursor[d4.z], 1);
    int p3 = atomicAdd(&cursor[d4.w], 1);
    pairs[p0] = make_float2(__int_as_float(s4.x), w4.x);
    pairs[p1] = make_float2(__int_as_float(s4.y), w4.y);
    pairs[p2] = make_float2(__int_as_float(s4.z), w4.z);
    pairs[p3] = make_float2(__int_as_float(s4.w), w4.w);
}

// ---------------- 4a) gather-only: agg[n] = sum w * x[src]  ----------------
// No LDS, no W1, no BN -> minimal register pressure -> max resident waves.
// Lane = feature; 16-deep unrolled loads, 2 accumulator chains.
#define G_NPW 5   // nodes per wave -> 5000 blocks
__global__ __launch_bounds__(256) void gather_kernel(
    const float* __restrict__ x,
    const int* __restrict__ rowstart,
    const float2* __restrict__ pairs,
    float* __restrict__ agg)
{
    const int tid  = threadIdx.x;
    const int lane = tid & 63;
    const int wid  = tid >> 6;
    const int node0 = (blockIdx.x * 4 + wid) * G_NPW;

    for (int r = 0; r < G_NPW; ++r) {
        const int n  = node0 + r;
        const int jb = rowstart[n];
        const int je = rowstart[n + 1];
        float accA = 0.f, accB = 0.f;
        for (int j0 = jb; j0 < je; j0 += 64) {
            const int cnt = min(64, je - j0);
            float2 p = (lane < cnt) ? pairs[j0 + lane] : make_float2(0.f, 0.f);
            int   psrc = __float_as_int(p.x);
            float pw   = p.y;
            const int nch = (cnt + 15) >> 4;
            for (int c = 0; c < nch; ++c) {
                const int base = c * 16;
                #pragma unroll
                for (int t = 0; t < 16; t += 2) {
                    int   sA = __shfl(psrc, base + t);
                    float wA = __shfl(pw,   base + t);
                    int   sB = __shfl(psrc, base + t + 1);
                    float wB = __shfl(pw,   base + t + 1);
                    accA += wA * x[(size_t)sA * IN_DIM + lane];
                    accB += wB * x[(size_t)sB * IN_DIM + lane];
                }
            }
        }
        agg[(size_t)n * IN_DIM + lane] = accA + accB;   // single coalesced store
    }
}

// ---------------- 4b) streaming GEMV: h = (agg + x) @ W1 + b1, + BN partials --
#define M_NPW 25   // nodes per wave -> 1000 blocks
__global__ __launch_bounds__(256) void gemv_kernel(
    const float* __restrict__ agg,
    const float* __restrict__ x,
    const float* __restrict__ W1,   // [64,128] row-major
    const float* __restrict__ b1,
    float* __restrict__ h,          // [N,128]
    float* __restrict__ gsum, float* __restrict__ gsum2)
{
    __shared__ float w1s[IN_DIM][EMB];     // 32 KB
    __shared__ float rowbuf[4][IN_DIM];
    __shared__ float red[4][2][EMB];

    const int tid  = threadIdx.x;
    const int lane = tid & 63;
    const int wid  = tid >> 6;
    const int lane64 = lane + 64;

    for (int i = tid; i < IN_DIM * EMB; i += 256)
        w1s[i >> 7][i & 127] = W1[i];
    const float bl0 = b1[lane], bl1 = b1[lane64];
    __syncthreads();

    float s0 = 0.f, s20 = 0.f, s1 = 0.f, s21 = 0.f;
    const int node0 = (blockIdx.x * 4 + wid) * M_NPW;

    for (int r = 0; r < M_NPW; ++r) {
        const int n = node0 + r;
        // wave-private LDS row (same-wave write->read)
        rowbuf[wid][lane] = agg[(size_t)n * IN_DIM + lane]
                          + x[(size_t)n * IN_DIM + lane];   // self term (1+eps)=1

        float a0 = bl0, a1 = bl1;
        const float4* rb4 = (const float4*)rowbuf[wid];
        #pragma unroll
        for (int kg = 0; kg < 16; ++kg) {
            float4 rv = rb4[kg];
            int k = kg * 4;
            a0 += rv.x * w1s[k][lane]   + rv.y * w1s[k+1][lane]
                + rv.z * w1s[k+2][lane] + rv.w * w1s[k+3][lane];
            a1 += rv.x * w1s[k][lane64]   + rv.y * w1s[k+1][lane64]
                + rv.z * w1s[k+2][lane64] + rv.w * w1s[k+3][lane64];
        }
        h[(size_t)n * EMB + lane]   = a0;
        h[(size_t)n * EMB + lane64] = a1;
        s0 += a0; s20 += a0 * a0;
        s1 += a1; s21 += a1 * a1;
    }

    red[wid][0][lane] = s0;  red[wid][0][lane64] = s1;
    red[wid][1][lane] = s20; red[wid][1][lane64] = s21;
    __syncthreads();
    if (tid < EMB) {
        float t0 = red[0][0][tid] + red[1][0][tid] + red[2][0][tid] + red[3][0][tid];
        float t1 = red[0][1][tid] + red[1][1][tid] + red[2][1][tid] + red[3][1][tid];
        atomicAdd(&gsum[tid],  t0);
        atomicAdd(&gsum2[tid], t1);
    }
}

// ---------------- 4-fallback) fused gather+GEMV (round-5 structure, fp32) ----
#define B1_NPW 5
__global__ __launch_bounds__(256) void mlp1_fused_kernel(
    const float* __restrict__ x,
    const int* __restrict__ rowstart,
    const float2* __restrict__ pairs,
    const float* __restrict__ W1,
    const float* __restrict__ b1,
    float* __restrict__ h,
    float* __restrict__ gsum, float* __restrict__ gsum2)
{
    __shared__ float w1s[IN_DIM][EMB];
    __shared__ float rowbuf[4][IN_DIM];
    __shared__ float red[4][2][EMB];

    const int tid  = threadIdx.x;
    const int lane = tid & 63;
    const int wid  = tid >> 6;
    const int lane64 = lane + 64;

    for (int i = tid; i < IN_DIM * EMB; i += 256)
        w1s[i >> 7][i & 127] = W1[i];
    const float bl0 = b1[lane], bl1 = b1[lane64];
    __syncthreads();

    float s0 = 0.f, s20 = 0.f, s1 = 0.f, s21 = 0.f;
    const int node0 = (blockIdx.x * 4 + wid) * B1_NPW;

    for (int r = 0; r < B1_NPW; ++r) {
        const int n  = node0 + r;
        const int jb = rowstart[n];
        const int je = rowstart[n + 1];
        float accA = x[(size_t)n * IN_DIM + lane];
        float accB = 0.f;
        for (int j0 = jb; j0 < je; j0 += 64) {
            const int cnt = min(64, je - j0);
            float2 p = (lane < cnt) ? pairs[j0 + lane] : make_float2(0.f, 0.f);
            int   psrc = __float_as_int(p.x);
            float pw   = p.y;
            const int nch = (cnt + 15) >> 4;
            for (int c = 0; c < nch; ++c) {
                const int base = c * 16;
                #pragma unroll
                for (int t = 0; t < 16; t += 2) {
                    int   sA = __shfl(psrc, base + t);
                    float wA = __shfl(pw,   base + t);
                    int   sB = __shfl(psrc, base + t + 1);
                    float wB = __shfl(pw,   base + t + 1);
                    accA += wA * x[(size_t)sA * IN_DIM + lane];
                    accB += wB * x[(size_t)sB * IN_DIM + lane];
                }
            }
        }
        rowbuf[wid][lane] = accA + accB;
        float a0 = bl0, a1 = bl1;
        const float4* rb4 = (const float4*)rowbuf[wid];
        #pragma unroll
        for (int kg = 0; kg < 16; ++kg) {
            float4 rv = rb4[kg];
            int k = kg * 4;
            a0 += rv.x * w1s[k][lane]   + rv.y * w1s[k+1][lane]
                + rv.z * w1s[k+2][lane] + rv.w * w1s[k+3][lane];
            a1 += rv.x * w1s[k][lane64]   + rv.y * w1s[k+1][lane64]
                + rv.z * w1s[k+2][lane64] + rv.w * w1s[k+3][lane64];
        }
        h[(size_t)n * EMB + lane]   = a0;
        h[(size_t)n * EMB + lane64] = a1;
        s0 += a0; s20 += a0 * a0;
        s1 += a1; s21 += a1 * a1;
    }

    red[wid][0][lane] = s0;  red[wid][0][lane64] = s1;
    red[wid][1][lane] = s20; red[wid][1][lane64] = s21;
    __syncthreads();
    if (tid < EMB) {
        float t0 = red[0][0][tid] + red[1][0][tid] + red[2][0][tid] + red[3][0][tid];
        float t1 = red[0][1][tid] + red[1][1][tid] + red[2][1][tid] + red[3][1][tid];
        atomicAdd(&gsum[tid],  t0);
        atomicAdd(&gsum2[tid], t1);
    }
}

// ---------------- 5) out = relu(BN(h)) @ W2 + b2 (in-place on h) ----------------
#define E_ROWS 80
__global__ __launch_bounds__(256, 2) void mlp2_kernel(
    float* __restrict__ hio,
    const float* __restrict__ gsum, const float* __restrict__ gsum2,
    const float* __restrict__ gamma, const float* __restrict__ beta,
    const float* __restrict__ W2,   // [128,128] row-major
    const float* __restrict__ b2)
{
    __shared__ float nbuf[8][EMB];    // 4 KB

    const int tid = threadIdx.x;
    const int col = tid & 127;
    const int rh  = tid >> 7;

    float w[EMB];
    #pragma unroll
    for (int k = 0; k < EMB; ++k) w[k] = W2[k * EMB + col];

    const float invN = 1.0f / (float)N_NODES;
    float mean = gsum[col] * invN;
    float var  = gsum2[col] * invN - mean * mean;
    float inv  = rsqrtf(var + BN_EPS);
    float a    = gamma[col] * inv;
    float bb   = beta[col] - mean * a;
    float bj   = b2[col];

    const int row0 = blockIdx.x * E_ROWS;
    for (int it = 0; it < E_ROWS / 8; ++it) {
        const int rbase = row0 + it * 8;
        __syncthreads();
        #pragma unroll
        for (int rr = 0; rr < 4; ++rr) {
            int lr = rh * 4 + rr;
            float hv = hio[(size_t)(rbase + lr) * EMB + col];
            nbuf[lr][col] = fmaxf(hv * a + bb, 0.f);
        }
        __syncthreads();
        #pragma unroll
        for (int rr = 0; rr < 4; ++rr) {
            const int lr = rh * 4 + rr;
            const float4* nb4 = (const float4*)&nbuf[lr][0];
            float acc = bj;
            #pragma unroll
            for (int kg = 0; kg < 32; ++kg) {
                float4 nv = nb4[kg];
                acc += nv.x * w[kg*4+0] + nv.y * w[kg*4+1]
                     + nv.z * w[kg*4+2] + nv.w * w[kg*4+3];
            }
            hio[(size_t)(rbase + lr) * EMB + col] = acc;
        }
    }
}

extern "C" void kernel_launch(void* const* d_in, const int* in_sizes, int n_in,
                              void* d_out, int out_size, void* d_ws, size_t ws_size,
                              hipStream_t stream)
{
    const float* x     = (const float*)d_in[0];
    const int*   ei    = (const int*)d_in[1];   // int32 [2,E]
    const float* ew    = (const float*)d_in[3];
    const float* W1    = (const float*)d_in[4];
    const float* b1    = (const float*)d_in[5];
    const float* gamma = (const float*)d_in[6];
    const float* beta  = (const float*)d_in[7];
    const float* W2    = (const float*)d_in[8];
    const float* b2    = (const float*)d_in[9];

    char* ws = (char*)d_ws;
    int*    rowstart = (int*)(ws + WS_ROWSTART);
    int*    cursor   = (int*)(ws + WS_CURSOR);
    float*  gsum     = (float*)(ws + WS_GSUM);
    float*  gsum2    = (float*)(ws + WS_GSUM2);
    int*    bsum     = (int*)(ws + WS_BSUM);
    float2* pairs    = (float2*)(ws + WS_PAIRS);
    float*  agg      = (float*)(ws + WS_AGG);
    float*  h        = (float*)d_out;

    const bool split = (ws_size >= WS_NEED_SPLIT);

    hipMemsetAsync(d_ws, 0, WS_ZERO_BYTES, stream);

    hist_kernel<<<(N_EDGES / 4 + 255) / 256, 256, 0, stream>>>(ei, rowstart);
    scan1_kernel<<<S1_BLOCKS, 256, 0, stream>>>(rowstart, bsum);
    scan2_kernel<<<1, 128, 0, stream>>>(bsum);
    scan3_kernel<<<S1_BLOCKS, 256, 0, stream>>>(rowstart, cursor, bsum);
    fill_kernel<<<(N_EDGES / 4 + 255) / 256, 256, 0, stream>>>(ei, ew, cursor, pairs);
    if (split) {
        gather_kernel<<<N_NODES / (4 * G_NPW), 256, 0, stream>>>(x, rowstart, pairs, agg);
        gemv_kernel<<<N_NODES / (4 * M_NPW), 256, 0, stream>>>(agg, x, W1, b1, h, gsum, gsum2);
    } else {
        mlp1_fused_kernel<<<N_NODES / (4 * B1_NPW), 256, 0, stream>>>(
            x, rowstart, pairs, W1, b1, h, gsum, gsum2);
    }
    mlp2_kernel<<<N_NODES / E_ROWS, 256, 0, stream>>>(h, gsum, gsum2, gamma, beta, W2, b2);
}

// Round 11
// 398.451 us; speedup vs baseline: 2.0732x; 1.1257x over previous
//
#include <hip/hip_runtime.h>

#define N_NODES 100000
#define IN_DIM 64
#define EMB 128
#define N_EDGES 1600000
#define BN_EPS 1e-5f

#define SCAN_ELEMS (N_NODES + 1)        // 100001
#define S1_EPB 1024
#define S1_BLOCKS ((SCAN_ELEMS + S1_EPB - 1) / S1_EPB)   // 98

// ---- workspace layout (bytes) ----
#define WS_ROWSTART 0
#define WS_GSUM     400128
#define WS_GSUM2    400640
#define WS_CURSOR   401152
#define WS_BSUM     801280
#define WS_PAIRS    801792
#define WS_AGG      13601792                 // pairs + 12.8 MB
#define WS_NEED_SPLIT 39201792ULL            // agg + 25.6 MB
#define WS_ZERO_BYTES 401152

// ---------------- 1) histogram of dst (4 edges/thread) ----------------
__global__ __launch_bounds__(256) void hist_kernel(
    const int* __restrict__ ei, int* __restrict__ rowstart)
{
    int e0 = (blockIdx.x * 256 + threadIdx.x) * 4;
    if (e0 >= N_EDGES) return;
    int4 d4 = *(const int4*)(ei + N_EDGES + e0);
    atomicAdd(&rowstart[1 + d4.x], 1);
    atomicAdd(&rowstart[1 + d4.y], 1);
    atomicAdd(&rowstart[1 + d4.z], 1);
    atomicAdd(&rowstart[1 + d4.w], 1);
}

// ---------------- 2a) per-block reduce of counts ----------------
__global__ __launch_bounds__(256) void scan1_kernel(
    const int* __restrict__ rowstart, int* __restrict__ bsum)
{
    __shared__ int red[256];
    const int t = threadIdx.x;
    const int base = blockIdx.x * S1_EPB + t * 4;
    int s = 0;
    #pragma unroll
    for (int k = 0; k < 4; ++k) {
        int idx = base + k;
        if (idx < SCAN_ELEMS) s += rowstart[idx];
    }
    red[t] = s;
    __syncthreads();
    for (int off = 128; off > 0; off >>= 1) {
        if (t < off) red[t] += red[t + off];
        __syncthreads();
    }
    if (t == 0) bsum[blockIdx.x] = red[0];
}

// ---------------- 2b) exclusive scan of block sums ----------------
__global__ __launch_bounds__(128) void scan2_kernel(int* __restrict__ bsum)
{
    __shared__ int buf[128];
    const int t = threadIdx.x;
    buf[t] = (t < S1_BLOCKS) ? bsum[t] : 0;
    __syncthreads();
    for (int off = 1; off < 128; off <<= 1) {
        int v = (t >= off) ? buf[t - off] : 0;
        __syncthreads();
        buf[t] += v;
        __syncthreads();
    }
    if (t < S1_BLOCKS) bsum[t] = (t > 0) ? buf[t - 1] : 0;
}

// ---------------- 2c) block-local inclusive scan + offset ----------------
__global__ __launch_bounds__(256) void scan3_kernel(
    int* __restrict__ rowstart, int* __restrict__ cursor,
    const int* __restrict__ bsum)
{
    __shared__ int tsum[256];
    const int t = threadIdx.x;
    const int base = blockIdx.x * S1_EPB + t * 4;
    int c0 = 0, c1 = 0, c2 = 0, c3 = 0;
    if (base + 0 < SCAN_ELEMS) c0 = rowstart[base + 0];
    if (base + 1 < SCAN_ELEMS) c1 = rowstart[base + 1];
    if (base + 2 < SCAN_ELEMS) c2 = rowstart[base + 2];
    if (base + 3 < SCAN_ELEMS) c3 = rowstart[base + 3];
    const int i0 = c0, i1 = i0 + c1, i2 = i1 + c2, i3 = i2 + c3;
    tsum[t] = i3;
    __syncthreads();
    for (int off = 1; off < 256; off <<= 1) {
        int v = (t >= off) ? tsum[t - off] : 0;
        __syncthreads();
        tsum[t] += v;
        __syncthreads();
    }
    const int boff = bsum[blockIdx.x] + tsum[t] - i3;
    const int r0 = boff + i0, r1 = boff + i1, r2 = boff + i2, r3 = boff + i3;
    if (base + 0 < SCAN_ELEMS) rowstart[base + 0] = r0;
    if (base + 1 < SCAN_ELEMS) rowstart[base + 1] = r1;
    if (base + 2 < SCAN_ELEMS) rowstart[base + 2] = r2;
    if (base + 3 < SCAN_ELEMS) rowstart[base + 3] = r3;
    if (base + 0 < N_NODES) cursor[base + 0] = r0;
    if (base + 1 < N_NODES) cursor[base + 1] = r1;
    if (base + 2 < N_NODES) cursor[base + 2] = r2;
    if (base + 3 < N_NODES) cursor[base + 3] = r3;
}

// ---------------- 3) fill (src, w) pairs — XCD-confined scatter ----------------
// dst space split into 8 ranges of 12500 nodes. Block b handles range b%8 and
// edge-stripe b/8. Workgroups round-robin across the 8 XCDs, so range g's pairs
// region (~1.6 MB) is written only from XCD g -> lines assemble in its L2
// instead of 8 partially-dirty copies (r10: WRITE_SIZE 100 MB = 64 B/edge).
// Locality heuristic only; correctness doesn't depend on the XCD mapping.
#define F_GROUPS 8
#define F_RANGE  (N_NODES / F_GROUPS)     // 12500
#define F_STRIPE 8192
#define F_NSTRIPE ((N_EDGES + F_STRIPE - 1) / F_STRIPE)  // 196
__global__ __launch_bounds__(256) void fill_kernel(
    const int* __restrict__ ei, const float* __restrict__ ew,
    int* __restrict__ cursor, float2* __restrict__ pairs)
{
    const int g  = blockIdx.x & (F_GROUPS - 1);
    const int s  = blockIdx.x / F_GROUPS;
    const int lo = g * F_RANGE;
    const int hi = lo + F_RANGE;
    const int ebase = s * F_STRIPE;
    #pragma unroll
    for (int i = 0; i < F_STRIPE / 1024; ++i) {   // 8 iters of 4 edges/thread
        int e0 = ebase + (i * 256 + threadIdx.x) * 4;
        if (e0 >= N_EDGES) continue;
        int4 d4 = *(const int4*)(ei + N_EDGES + e0);
        bool mx = (d4.x >= lo) & (d4.x < hi);
        bool my = (d4.y >= lo) & (d4.y < hi);
        bool mz = (d4.z >= lo) & (d4.z < hi);
        bool mw = (d4.w >= lo) & (d4.w < hi);
        if (!(mx | my | mz | mw)) continue;       // skip src/w loads (~58% of quads)
        int4   s4 = *(const int4*)(ei + e0);
        float4 w4 = *(const float4*)(ew + e0);
        if (mx) { int p = atomicAdd(&cursor[d4.x], 1); pairs[p] = make_float2(__int_as_float(s4.x), w4.x); }
        if (my) { int p = atomicAdd(&cursor[d4.y], 1); pairs[p] = make_float2(__int_as_float(s4.y), w4.y); }
        if (mz) { int p = atomicAdd(&cursor[d4.z], 1); pairs[p] = make_float2(__int_as_float(s4.z), w4.z); }
        if (mw) { int p = atomicAdd(&cursor[d4.w], 1); pairs[p] = make_float2(__int_as_float(s4.w), w4.w); }
    }
}

// ---------------- 4a) gather-only: agg[n] = sum w * x[src]  ----------------
#define G_NPW 5   // nodes per wave -> 5000 blocks
__global__ __launch_bounds__(256) void gather_kernel(
    const float* __restrict__ x,
    const int* __restrict__ rowstart,
    const float2* __restrict__ pairs,
    float* __restrict__ agg)
{
    const int tid  = threadIdx.x;
    const int lane = tid & 63;
    const int wid  = tid >> 6;
    const int node0 = (blockIdx.x * 4 + wid) * G_NPW;

    for (int r = 0; r < G_NPW; ++r) {
        const int n  = node0 + r;
        const int jb = rowstart[n];
        const int je = rowstart[n + 1];
        float accA = 0.f, accB = 0.f;
        for (int j0 = jb; j0 < je; j0 += 64) {
            const int cnt = min(64, je - j0);
            float2 p = (lane < cnt) ? pairs[j0 + lane] : make_float2(0.f, 0.f);
            int   psrc = __float_as_int(p.x);
            float pw   = p.y;
            const int nch = (cnt + 15) >> 4;
            for (int c = 0; c < nch; ++c) {
                const int base = c * 16;
                #pragma unroll
                for (int t = 0; t < 16; t += 2) {
                    int   sA = __shfl(psrc, base + t);
                    float wA = __shfl(pw,   base + t);
                    int   sB = __shfl(psrc, base + t + 1);
                    float wB = __shfl(pw,   base + t + 1);
                    accA += wA * x[(size_t)sA * IN_DIM + lane];
                    accB += wB * x[(size_t)sB * IN_DIM + lane];
                }
            }
        }
        agg[(size_t)n * IN_DIM + lane] = accA + accB;   // single coalesced store
    }
}

// ---------------- 4b) streaming GEMV: h = (agg + x) @ W1 + b1, + BN partials --
#define M_NPW 25   // nodes per wave -> 1000 blocks
__global__ __launch_bounds__(256) void gemv_kernel(
    const float* __restrict__ agg,
    const float* __restrict__ x,
    const float* __restrict__ W1,   // [64,128] row-major
    const float* __restrict__ b1,
    float* __restrict__ h,          // [N,128]
    float* __restrict__ gsum, float* __restrict__ gsum2)
{
    __shared__ float w1s[IN_DIM][EMB];     // 32 KB
    __shared__ float rowbuf[4][IN_DIM];
    __shared__ float red[4][2][EMB];

    const int tid  = threadIdx.x;
    const int lane = tid & 63;
    const int wid  = tid >> 6;
    const int lane64 = lane + 64;

    for (int i = tid; i < IN_DIM * EMB; i += 256)
        w1s[i >> 7][i & 127] = W1[i];
    const float bl0 = b1[lane], bl1 = b1[lane64];
    __syncthreads();

    float s0 = 0.f, s20 = 0.f, s1 = 0.f, s21 = 0.f;
    const int node0 = (blockIdx.x * 4 + wid) * M_NPW;

    for (int r = 0; r < M_NPW; ++r) {
        const int n = node0 + r;
        rowbuf[wid][lane] = agg[(size_t)n * IN_DIM + lane]
                          + x[(size_t)n * IN_DIM + lane];   // self term (1+eps)=1

        float a0 = bl0, a1 = bl1;
        const float4* rb4 = (const float4*)rowbuf[wid];
        #pragma unroll
        for (int kg = 0; kg < 16; ++kg) {
            float4 rv = rb4[kg];
            int k = kg * 4;
            a0 += rv.x * w1s[k][lane]   + rv.y * w1s[k+1][lane]
                + rv.z * w1s[k+2][lane] + rv.w * w1s[k+3][lane];
            a1 += rv.x * w1s[k][lane64]   + rv.y * w1s[k+1][lane64]
                + rv.z * w1s[k+2][lane64] + rv.w * w1s[k+3][lane64];
        }
        h[(size_t)n * EMB + lane]   = a0;
        h[(size_t)n * EMB + lane64] = a1;
        s0 += a0; s20 += a0 * a0;
        s1 += a1; s21 += a1 * a1;
    }

    red[wid][0][lane] = s0;  red[wid][0][lane64] = s1;
    red[wid][1][lane] = s20; red[wid][1][lane64] = s21;
    __syncthreads();
    if (tid < EMB) {
        float t0 = red[0][0][tid] + red[1][0][tid] + red[2][0][tid] + red[3][0][tid];
        float t1 = red[0][1][tid] + red[1][1][tid] + red[2][1][tid] + red[3][1][tid];
        atomicAdd(&gsum[tid],  t0);
        atomicAdd(&gsum2[tid], t1);
    }
}

// ---------------- 4-fallback) fused gather+GEMV (round-5 structure, fp32) ----
#define B1_NPW 5
__global__ __launch_bounds__(256) void mlp1_fused_kernel(
    const float* __restrict__ x,
    const int* __restrict__ rowstart,
    const float2* __restrict__ pairs,
    const float* __restrict__ W1,
    const float* __restrict__ b1,
    float* __restrict__ h,
    float* __restrict__ gsum, float* __restrict__ gsum2)
{
    __shared__ float w1s[IN_DIM][EMB];
    __shared__ float rowbuf[4][IN_DIM];
    __shared__ float red[4][2][EMB];

    const int tid  = threadIdx.x;
    const int lane = tid & 63;
    const int wid  = tid >> 6;
    const int lane64 = lane + 64;

    for (int i = tid; i < IN_DIM * EMB; i += 256)
        w1s[i >> 7][i & 127] = W1[i];
    const float bl0 = b1[lane], bl1 = b1[lane64];
    __syncthreads();

    float s0 = 0.f, s20 = 0.f, s1 = 0.f, s21 = 0.f;
    const int node0 = (blockIdx.x * 4 + wid) * B1_NPW;

    for (int r = 0; r < B1_NPW; ++r) {
        const int n  = node0 + r;
        const int jb = rowstart[n];
        const int je = rowstart[n + 1];
        float accA = x[(size_t)n * IN_DIM + lane];
        float accB = 0.f;
        for (int j0 = jb; j0 < je; j0 += 64) {
            const int cnt = min(64, je - j0);
            float2 p = (lane < cnt) ? pairs[j0 + lane] : make_float2(0.f, 0.f);
            int   psrc = __float_as_int(p.x);
            float pw   = p.y;
            const int nch = (cnt + 15) >> 4;
            for (int c = 0; c < nch; ++c) {
                const int base = c * 16;
                #pragma unroll
                for (int t = 0; t < 16; t += 2) {
                    int   sA = __shfl(psrc, base + t);
                    float wA = __shfl(pw,   base + t);
                    int   sB = __shfl(psrc, base + t + 1);
                    float wB = __shfl(pw,   base + t + 1);
                    accA += wA * x[(size_t)sA * IN_DIM + lane];
                    accB += wB * x[(size_t)sB * IN_DIM + lane];
                }
            }
        }
        rowbuf[wid][lane] = accA + accB;
        float a0 = bl0, a1 = bl1;
        const float4* rb4 = (const float4*)rowbuf[wid];
        #pragma unroll
        for (int kg = 0; kg < 16; ++kg) {
            float4 rv = rb4[kg];
            int k = kg * 4;
            a0 += rv.x * w1s[k][lane]   + rv.y * w1s[k+1][lane]
                + rv.z * w1s[k+2][lane] + rv.w * w1s[k+3][lane];
            a1 += rv.x * w1s[k][lane64]   + rv.y * w1s[k+1][lane64]
                + rv.z * w1s[k+2][lane64] + rv.w * w1s[k+3][lane64];
        }
        h[(size_t)n * EMB + lane]   = a0;
        h[(size_t)n * EMB + lane64] = a1;
        s0 += a0; s20 += a0 * a0;
        s1 += a1; s21 += a1 * a1;
    }

    red[wid][0][lane] = s0;  red[wid][0][lane64] = s1;
    red[wid][1][lane] = s20; red[wid][1][lane64] = s21;
    __syncthreads();
    if (tid < EMB) {
        float t0 = red[0][0][tid] + red[1][0][tid] + red[2][0][tid] + red[3][0][tid];
        float t1 = red[0][1][tid] + red[1][1][tid] + red[2][1][tid] + red[3][1][tid];
        atomicAdd(&gsum[tid],  t0);
        atomicAdd(&gsum2[tid], t1);
    }
}

// ---------------- 5) out = relu(BN(h)) @ W2 + b2 (in-place on h) ----------------
#define E_ROWS 80
__global__ __launch_bounds__(256, 2) void mlp2_kernel(
    float* __restrict__ hio,
    const float* __restrict__ gsum, const float* __restrict__ gsum2,
    const float* __restrict__ gamma, const float* __restrict__ beta,
    const float* __restrict__ W2,   // [128,128] row-major
    const float* __restrict__ b2)
{
    __shared__ float nbuf[8][EMB];    // 4 KB

    const int tid = threadIdx.x;
    const int col = tid & 127;
    const int rh  = tid >> 7;

    float w[EMB];
    #pragma unroll
    for (int k = 0; k < EMB; ++k) w[k] = W2[k * EMB + col];

    const float invN = 1.0f / (float)N_NODES;
    float mean = gsum[col] * invN;
    float var  = gsum2[col] * invN - mean * mean;
    float inv  = rsqrtf(var + BN_EPS);
    float a    = gamma[col] * inv;
    float bb   = beta[col] - mean * a;
    float bj   = b2[col];

    const int row0 = blockIdx.x * E_ROWS;
    for (int it = 0; it < E_ROWS / 8; ++it) {
        const int rbase = row0 + it * 8;
        __syncthreads();
        #pragma unroll
        for (int rr = 0; rr < 4; ++rr) {
            int lr = rh * 4 + rr;
            float hv = hio[(size_t)(rbase + lr) * EMB + col];
            nbuf[lr][col] = fmaxf(hv * a + bb, 0.f);
        }
        __syncthreads();
        #pragma unroll
        for (int rr = 0; rr < 4; ++rr) {
            const int lr = rh * 4 + rr;
            const float4* nb4 = (const float4*)&nbuf[lr][0];
            float acc = bj;
            #pragma unroll
            for (int kg = 0; kg < 32; ++kg) {
                float4 nv = nb4[kg];
                acc += nv.x * w[kg*4+0] + nv.y * w[kg*4+1]
                     + nv.z * w[kg*4+2] + nv.w * w[kg*4+3];
            }
            hio[(size_t)(rbase + lr) * EMB + col] = acc;
        }
    }
}

extern "C" void kernel_launch(void* const* d_in, const int* in_sizes, int n_in,
                              void* d_out, int out_size, void* d_ws, size_t ws_size,
                              hipStream_t stream)
{
    const float* x     = (const float*)d_in[0];
    const int*   ei    = (const int*)d_in[1];   // int32 [2,E]
    const float* ew    = (const float*)d_in[3];
    const float* W1    = (const float*)d_in[4];
    const float* b1    = (const float*)d_in[5];
    const float* gamma = (const float*)d_in[6];
    const float* beta  = (const float*)d_in[7];
    const float* W2    = (const float*)d_in[8];
    const float* b2    = (const float*)d_in[9];

    char* ws = (char*)d_ws;
    int*    rowstart = (int*)(ws + WS_ROWSTART);
    int*    cursor   = (int*)(ws + WS_CURSOR);
    float*  gsum     = (float*)(ws + WS_GSUM);
    float*  gsum2    = (float*)(ws + WS_GSUM2);
    int*    bsum     = (int*)(ws + WS_BSUM);
    float2* pairs    = (float2*)(ws + WS_PAIRS);
    float*  agg      = (float*)(ws + WS_AGG);
    float*  h        = (float*)d_out;

    const bool split = (ws_size >= WS_NEED_SPLIT);

    hipMemsetAsync(d_ws, 0, WS_ZERO_BYTES, stream);

    hist_kernel<<<(N_EDGES / 4 + 255) / 256, 256, 0, stream>>>(ei, rowstart);
    scan1_kernel<<<S1_BLOCKS, 256, 0, stream>>>(rowstart, bsum);
    scan2_kernel<<<1, 128, 0, stream>>>(bsum);
    scan3_kernel<<<S1_BLOCKS, 256, 0, stream>>>(rowstart, cursor, bsum);
    fill_kernel<<<F_NSTRIPE * F_GROUPS, 256, 0, stream>>>(ei, ew, cursor, pairs);
    if (split) {
        gather_kernel<<<N_NODES / (4 * G_NPW), 256, 0, stream>>>(x, rowstart, pairs, agg);
        gemv_kernel<<<N_NODES / (4 * M_NPW), 256, 0, stream>>>(agg, x, W1, b1, h, gsum, gsum2);
    } else {
        mlp1_fused_kernel<<<N_NODES / (4 * B1_NPW), 256, 0, stream>>>(
            x, rowstart, pairs, W1, b1, h, gsum, gsum2);
    }
    mlp2_kernel<<<N_NODES / E_ROWS, 256, 0, stream>>>(h, gsum, gsum2, gamma, beta, W2, b2);
}

// Round 12
// 397.866 us; speedup vs baseline: 2.0763x; 1.0015x over previous
//
#include <hip/hip_runtime.h>

#define N_NODES 100000
#define IN_DIM 64
#define EMB 128
#define N_EDGES 1600000
#define BN_EPS 1e-5f

#define SCAN_ELEMS (N_NODES + 1)        // 100001
#define S1_EPB 1024
#define S1_BLOCKS ((SCAN_ELEMS + S1_EPB - 1) / S1_EPB)   // 98

// ---- workspace layout (bytes) ----
#define WS_ROWSTART 0
#define WS_GSUM     400128
#define WS_GSUM2    400640
#define WS_CURSOR   401152
#define WS_BSUM     801280
#define WS_PAIRS    801792
#define WS_AGG      13601792                 // pairs + 12.8 MB
#define WS_NEED_SPLIT 39201792ULL            // agg + 25.6 MB
#define WS_ZERO_BYTES 401152

// ---------------- 1) histogram of dst (4 edges/thread) ----------------
__global__ __launch_bounds__(256) void hist_kernel(
    const int* __restrict__ ei, int* __restrict__ rowstart)
{
    int e0 = (blockIdx.x * 256 + threadIdx.x) * 4;
    if (e0 >= N_EDGES) return;
    int4 d4 = *(const int4*)(ei + N_EDGES + e0);
    atomicAdd(&rowstart[1 + d4.x], 1);
    atomicAdd(&rowstart[1 + d4.y], 1);
    atomicAdd(&rowstart[1 + d4.z], 1);
    atomicAdd(&rowstart[1 + d4.w], 1);
}

// ---------------- 2a) per-block reduce of counts ----------------
__global__ __launch_bounds__(256) void scan1_kernel(
    const int* __restrict__ rowstart, int* __restrict__ bsum)
{
    __shared__ int red[256];
    const int t = threadIdx.x;
    const int base = blockIdx.x * S1_EPB + t * 4;
    int s = 0;
    #pragma unroll
    for (int k = 0; k < 4; ++k) {
        int idx = base + k;
        if (idx < SCAN_ELEMS) s += rowstart[idx];
    }
    red[t] = s;
    __syncthreads();
    for (int off = 128; off > 0; off >>= 1) {
        if (t < off) red[t] += red[t + off];
        __syncthreads();
    }
    if (t == 0) bsum[blockIdx.x] = red[0];
}

// ---------------- 2b) exclusive scan of block sums ----------------
__global__ __launch_bounds__(128) void scan2_kernel(int* __restrict__ bsum)
{
    __shared__ int buf[128];
    const int t = threadIdx.x;
    buf[t] = (t < S1_BLOCKS) ? bsum[t] : 0;
    __syncthreads();
    for (int off = 1; off < 128; off <<= 1) {
        int v = (t >= off) ? buf[t - off] : 0;
        __syncthreads();
        buf[t] += v;
        __syncthreads();
    }
    if (t < S1_BLOCKS) bsum[t] = (t > 0) ? buf[t - 1] : 0;
}

// ---------------- 2c) block-local inclusive scan + offset ----------------
__global__ __launch_bounds__(256) void scan3_kernel(
    int* __restrict__ rowstart, int* __restrict__ cursor,
    const int* __restrict__ bsum)
{
    __shared__ int tsum[256];
    const int t = threadIdx.x;
    const int base = blockIdx.x * S1_EPB + t * 4;
    int c0 = 0, c1 = 0, c2 = 0, c3 = 0;
    if (base + 0 < SCAN_ELEMS) c0 = rowstart[base + 0];
    if (base + 1 < SCAN_ELEMS) c1 = rowstart[base + 1];
    if (base + 2 < SCAN_ELEMS) c2 = rowstart[base + 2];
    if (base + 3 < SCAN_ELEMS) c3 = rowstart[base + 3];
    const int i0 = c0, i1 = i0 + c1, i2 = i1 + c2, i3 = i2 + c3;
    tsum[t] = i3;
    __syncthreads();
    for (int off = 1; off < 256; off <<= 1) {
        int v = (t >= off) ? tsum[t - off] : 0;
        __syncthreads();
        tsum[t] += v;
        __syncthreads();
    }
    const int boff = bsum[blockIdx.x] + tsum[t] - i3;
    const int r0 = boff + i0, r1 = boff + i1, r2 = boff + i2, r3 = boff + i3;
    if (base + 0 < SCAN_ELEMS) rowstart[base + 0] = r0;
    if (base + 1 < SCAN_ELEMS) rowstart[base + 1] = r1;
    if (base + 2 < SCAN_ELEMS) rowstart[base + 2] = r2;
    if (base + 3 < SCAN_ELEMS) rowstart[base + 3] = r3;
    if (base + 0 < N_NODES) cursor[base + 0] = r0;
    if (base + 1 < N_NODES) cursor[base + 1] = r1;
    if (base + 2 < N_NODES) cursor[base + 2] = r2;
    if (base + 3 < N_NODES) cursor[base + 3] = r3;
}

// ---------------- 3) fill (src, w) pairs — XCD-confined scatter ----------------
#define F_GROUPS 8
#define F_RANGE  (N_NODES / F_GROUPS)     // 12500
#define F_STRIPE 8192
#define F_NSTRIPE ((N_EDGES + F_STRIPE - 1) / F_STRIPE)  // 196
__global__ __launch_bounds__(256) void fill_kernel(
    const int* __restrict__ ei, const float* __restrict__ ew,
    int* __restrict__ cursor, float2* __restrict__ pairs)
{
    const int g  = blockIdx.x & (F_GROUPS - 1);
    const int s  = blockIdx.x / F_GROUPS;
    const int lo = g * F_RANGE;
    const int hi = lo + F_RANGE;
    const int ebase = s * F_STRIPE;
    #pragma unroll
    for (int i = 0; i < F_STRIPE / 1024; ++i) {   // 8 iters of 4 edges/thread
        int e0 = ebase + (i * 256 + threadIdx.x) * 4;
        if (e0 >= N_EDGES) continue;
        int4 d4 = *(const int4*)(ei + N_EDGES + e0);
        bool mx = (d4.x >= lo) & (d4.x < hi);
        bool my = (d4.y >= lo) & (d4.y < hi);
        bool mz = (d4.z >= lo) & (d4.z < hi);
        bool mw = (d4.w >= lo) & (d4.w < hi);
        if (!(mx | my | mz | mw)) continue;
        int4   s4 = *(const int4*)(ei + e0);
        float4 w4 = *(const float4*)(ew + e0);
        if (mx) { int p = atomicAdd(&cursor[d4.x], 1); pairs[p] = make_float2(__int_as_float(s4.x), w4.x); }
        if (my) { int p = atomicAdd(&cursor[d4.y], 1); pairs[p] = make_float2(__int_as_float(s4.y), w4.y); }
        if (mz) { int p = atomicAdd(&cursor[d4.z], 1); pairs[p] = make_float2(__int_as_float(s4.z), w4.z); }
        if (mw) { int p = atomicAdd(&cursor[d4.w], 1); pairs[p] = make_float2(__int_as_float(s4.w), w4.w); }
    }
}

// ---------------- 4a) gather-only: agg[n] = sum w * x[src]  ----------------
#define G_NPW 5   // nodes per wave -> 5000 blocks
__global__ __launch_bounds__(256) void gather_kernel(
    const float* __restrict__ x,
    const int* __restrict__ rowstart,
    const float2* __restrict__ pairs,
    float* __restrict__ agg)
{
    const int tid  = threadIdx.x;
    const int lane = tid & 63;
    const int wid  = tid >> 6;
    const int node0 = (blockIdx.x * 4 + wid) * G_NPW;

    for (int r = 0; r < G_NPW; ++r) {
        const int n  = node0 + r;
        const int jb = rowstart[n];
        const int je = rowstart[n + 1];
        float accA = 0.f, accB = 0.f;
        for (int j0 = jb; j0 < je; j0 += 64) {
            const int cnt = min(64, je - j0);
            float2 p = (lane < cnt) ? pairs[j0 + lane] : make_float2(0.f, 0.f);
            int   psrc = __float_as_int(p.x);
            float pw   = p.y;
            const int nch = (cnt + 15) >> 4;
            for (int c = 0; c < nch; ++c) {
                const int base = c * 16;
                #pragma unroll
                for (int t = 0; t < 16; t += 2) {
                    int   sA = __shfl(psrc, base + t);
                    float wA = __shfl(pw,   base + t);
                    int   sB = __shfl(psrc, base + t + 1);
                    float wB = __shfl(pw,   base + t + 1);
                    accA += wA * x[(size_t)sA * IN_DIM + lane];
                    accB += wB * x[(size_t)sB * IN_DIM + lane];
                }
            }
        }
        agg[(size_t)n * IN_DIM + lane] = accA + accB;   // single coalesced store
    }
}

// ---------------- 4b) streaming GEMV: h = (agg + x) @ W1 + b1, + BN partials --
#define M_NPW 25   // nodes per wave -> 1000 blocks
__global__ __launch_bounds__(256) void gemv_kernel(
    const float* __restrict__ agg,
    const float* __restrict__ x,
    const float* __restrict__ W1,   // [64,128] row-major
    const float* __restrict__ b1,
    float* __restrict__ h,          // [N,128]
    float* __restrict__ gsum, float* __restrict__ gsum2)
{
    __shared__ float w1s[IN_DIM][EMB];     // 32 KB
    __shared__ float rowbuf[4][IN_DIM];
    __shared__ float red[4][2][EMB];

    const int tid  = threadIdx.x;
    const int lane = tid & 63;
    const int wid  = tid >> 6;
    const int lane64 = lane + 64;

    for (int i = tid; i < IN_DIM * EMB; i += 256)
        w1s[i >> 7][i & 127] = W1[i];
    const float bl0 = b1[lane], bl1 = b1[lane64];
    __syncthreads();

    float s0 = 0.f, s20 = 0.f, s1 = 0.f, s21 = 0.f;
    const int node0 = (blockIdx.x * 4 + wid) * M_NPW;

    for (int r = 0; r < M_NPW; ++r) {
        const int n = node0 + r;
        rowbuf[wid][lane] = agg[(size_t)n * IN_DIM + lane]
                          + x[(size_t)n * IN_DIM + lane];   // self term (1+eps)=1

        float a0 = bl0, a1 = bl1;
        const float4* rb4 = (const float4*)rowbuf[wid];
        #pragma unroll
        for (int kg = 0; kg < 16; ++kg) {
            float4 rv = rb4[kg];
            int k = kg * 4;
            a0 += rv.x * w1s[k][lane]   + rv.y * w1s[k+1][lane]
                + rv.z * w1s[k+2][lane] + rv.w * w1s[k+3][lane];
            a1 += rv.x * w1s[k][lane64]   + rv.y * w1s[k+1][lane64]
                + rv.z * w1s[k+2][lane64] + rv.w * w1s[k+3][lane64];
        }
        h[(size_t)n * EMB + lane]   = a0;
        h[(size_t)n * EMB + lane64] = a1;
        s0 += a0; s20 += a0 * a0;
        s1 += a1; s21 += a1 * a1;
    }

    red[wid][0][lane] = s0;  red[wid][0][lane64] = s1;
    red[wid][1][lane] = s20; red[wid][1][lane64] = s21;
    __syncthreads();
    if (tid < EMB) {
        float t0 = red[0][0][tid] + red[1][0][tid] + red[2][0][tid] + red[3][0][tid];
        float t1 = red[0][1][tid] + red[1][1][tid] + red[2][1][tid] + red[3][1][tid];
        atomicAdd(&gsum[tid],  t0);
        atomicAdd(&gsum2[tid], t1);
    }
}

// ---------------- 4-fallback) fused gather+GEMV (round-5 structure, fp32) ----
#define B1_NPW 5
__global__ __launch_bounds__(256) void mlp1_fused_kernel(
    const float* __restrict__ x,
    const int* __restrict__ rowstart,
    const float2* __restrict__ pairs,
    const float* __restrict__ W1,
    const float* __restrict__ b1,
    float* __restrict__ h,
    float* __restrict__ gsum, float* __restrict__ gsum2)
{
    __shared__ float w1s[IN_DIM][EMB];
    __shared__ float rowbuf[4][IN_DIM];
    __shared__ float red[4][2][EMB];

    const int tid  = threadIdx.x;
    const int lane = tid & 63;
    const int wid  = tid >> 6;
    const int lane64 = lane + 64;

    for (int i = tid; i < IN_DIM * EMB; i += 256)
        w1s[i >> 7][i & 127] = W1[i];
    const float bl0 = b1[lane], bl1 = b1[lane64];
    __syncthreads();

    float s0 = 0.f, s20 = 0.f, s1 = 0.f, s21 = 0.f;
    const int node0 = (blockIdx.x * 4 + wid) * B1_NPW;

    for (int r = 0; r < B1_NPW; ++r) {
        const int n  = node0 + r;
        const int jb = rowstart[n];
        const int je = rowstart[n + 1];
        float accA = x[(size_t)n * IN_DIM + lane];
        float accB = 0.f;
        for (int j0 = jb; j0 < je; j0 += 64) {
            const int cnt = min(64, je - j0);
            float2 p = (lane < cnt) ? pairs[j0 + lane] : make_float2(0.f, 0.f);
            int   psrc = __float_as_int(p.x);
            float pw   = p.y;
            const int nch = (cnt + 15) >> 4;
            for (int c = 0; c < nch; ++c) {
                const int base = c * 16;
                #pragma unroll
                for (int t = 0; t < 16; t += 2) {
                    int   sA = __shfl(psrc, base + t);
                    float wA = __shfl(pw,   base + t);
                    int   sB = __shfl(psrc, base + t + 1);
                    float wB = __shfl(pw,   base + t + 1);
                    accA += wA * x[(size_t)sA * IN_DIM + lane];
                    accB += wB * x[(size_t)sB * IN_DIM + lane];
                }
            }
        }
        rowbuf[wid][lane] = accA + accB;
        float a0 = bl0, a1 = bl1;
        const float4* rb4 = (const float4*)rowbuf[wid];
        #pragma unroll
        for (int kg = 0; kg < 16; ++kg) {
            float4 rv = rb4[kg];
            int k = kg * 4;
            a0 += rv.x * w1s[k][lane]   + rv.y * w1s[k+1][lane]
                + rv.z * w1s[k+2][lane] + rv.w * w1s[k+3][lane];
            a1 += rv.x * w1s[k][lane64]   + rv.y * w1s[k+1][lane64]
                + rv.z * w1s[k+2][lane64] + rv.w * w1s[k+3][lane64];
        }
        h[(size_t)n * EMB + lane]   = a0;
        h[(size_t)n * EMB + lane64] = a1;
        s0 += a0; s20 += a0 * a0;
        s1 += a1; s21 += a1 * a1;
    }

    red[wid][0][lane] = s0;  red[wid][0][lane64] = s1;
    red[wid][1][lane] = s20; red[wid][1][lane64] = s21;
    __syncthreads();
    if (tid < EMB) {
        float t0 = red[0][0][tid] + red[1][0][tid] + red[2][0][tid] + red[3][0][tid];
        float t1 = red[0][1][tid] + red[1][1][tid] + red[2][1][tid] + red[3][1][tid];
        atomicAdd(&gsum[tid],  t0);
        atomicAdd(&gsum2[tid], t1);
    }
}

// ---------------- 5) out = relu(BN(h)) @ W2 + b2 (in-place on h) ----------------
// NO min-waves clamp: (256,2) capped VGPR at 128 -> w[128] spilled (r11:
// VGPR_Count=84, VALUBusy 40%, 135 us). Plain bounds lets w[] live in regs
// (~170 VGPR, 3 waves/SIMD) -> VALU-throughput-bound.
#define E_ROWS 80
__global__ __launch_bounds__(256) void mlp2_kernel(
    float* __restrict__ hio,
    const float* __restrict__ gsum, const float* __restrict__ gsum2,
    const float* __restrict__ gamma, const float* __restrict__ beta,
    const float* __restrict__ W2,   // [128,128] row-major
    const float* __restrict__ b2)
{
    __shared__ float nbuf[8][EMB];    // 4 KB

    const int tid = threadIdx.x;
    const int col = tid & 127;
    const int rh  = tid >> 7;

    float w[EMB];
    #pragma unroll
    for (int k = 0; k < EMB; ++k) w[k] = W2[k * EMB + col];

    const float invN = 1.0f / (float)N_NODES;
    float mean = gsum[col] * invN;
    float var  = gsum2[col] * invN - mean * mean;
    float inv  = rsqrtf(var + BN_EPS);
    float a    = gamma[col] * inv;
    float bb   = beta[col] - mean * a;
    float bj   = b2[col];

    const int row0 = blockIdx.x * E_ROWS;
    for (int it = 0; it < E_ROWS / 8; ++it) {
        const int rbase = row0 + it * 8;
        __syncthreads();
        #pragma unroll
        for (int rr = 0; rr < 4; ++rr) {
            int lr = rh * 4 + rr;
            float hv = hio[(size_t)(rbase + lr) * EMB + col];
            nbuf[lr][col] = fmaxf(hv * a + bb, 0.f);
        }
        __syncthreads();
        #pragma unroll
        for (int rr = 0; rr < 4; ++rr) {
            const int lr = rh * 4 + rr;
            const float4* nb4 = (const float4*)&nbuf[lr][0];
            float acc = bj;
            #pragma unroll
            for (int kg = 0; kg < 32; ++kg) {
                float4 nv = nb4[kg];   // broadcast: all lanes same address
                acc += nv.x * w[kg*4+0] + nv.y * w[kg*4+1]
                     + nv.z * w[kg*4+2] + nv.w * w[kg*4+3];
            }
            hio[(size_t)(rbase + lr) * EMB + col] = acc;
        }
    }
}

extern "C" void kernel_launch(void* const* d_in, const int* in_sizes, int n_in,
                              void* d_out, int out_size, void* d_ws, size_t ws_size,
                              hipStream_t stream)
{
    const float* x     = (const float*)d_in[0];
    const int*   ei    = (const int*)d_in[1];   // int32 [2,E]
    const float* ew    = (const float*)d_in[3];
    const float* W1    = (const float*)d_in[4];
    const float* b1    = (const float*)d_in[5];
    const float* gamma = (const float*)d_in[6];
    const float* beta  = (const float*)d_in[7];
    const float* W2    = (const float*)d_in[8];
    const float* b2    = (const float*)d_in[9];

    char* ws = (char*)d_ws;
    int*    rowstart = (int*)(ws + WS_ROWSTART);
    int*    cursor   = (int*)(ws + WS_CURSOR);
    float*  gsum     = (float*)(ws + WS_GSUM);
    float*  gsum2    = (float*)(ws + WS_GSUM2);
    int*    bsum     = (int*)(ws + WS_BSUM);
    float2* pairs    = (float2*)(ws + WS_PAIRS);
    float*  agg      = (float*)(ws + WS_AGG);
    float*  h        = (float*)d_out;

    const bool split = (ws_size >= WS_NEED_SPLIT);

    hipMemsetAsync(d_ws, 0, WS_ZERO_BYTES, stream);

    hist_kernel<<<(N_EDGES / 4 + 255) / 256, 256, 0, stream>>>(ei, rowstart);
    scan1_kernel<<<S1_BLOCKS, 256, 0, stream>>>(rowstart, bsum);
    scan2_kernel<<<1, 128, 0, stream>>>(bsum);
    scan3_kernel<<<S1_BLOCKS, 256, 0, stream>>>(rowstart, cursor, bsum);
    fill_kernel<<<F_NSTRIPE * F_GROUPS, 256, 0, stream>>>(ei, ew, cursor, pairs);
    if (split) {
        gather_kernel<<<N_NODES / (4 * G_NPW), 256, 0, stream>>>(x, rowstart, pairs, agg);
        gemv_kernel<<<N_NODES / (4 * M_NPW), 256, 0, stream>>>(agg, x, W1, b1, h, gsum, gsum2);
    } else {
        mlp1_fused_kernel<<<N_NODES / (4 * B1_NPW), 256, 0, stream>>>(
            x, rowstart, pairs, W1, b1, h, gsum, gsum2);
    }
    mlp2_kernel<<<N_NODES / E_ROWS, 256, 0, stream>>>(h, gsum, gsum2, gamma, beta, W2, b2);
}

// Round 13
// 302.877 us; speedup vs baseline: 2.7274x; 1.3136x over previous
//
#include <hip/hip_runtime.h>

#define N_NODES 100000
#define IN_DIM 64
#define EMB 128
#define N_EDGES 1600000
#define BN_EPS 1e-5f

#define SCAN_ELEMS (N_NODES + 1)        // 100001
#define S1_EPB 1024
#define S1_BLOCKS ((SCAN_ELEMS + S1_EPB - 1) / S1_EPB)   // 98

// ---- workspace layout (bytes) ----
#define WS_ROWSTART 0
#define WS_GSUM     400128
#define WS_GSUM2    400640
#define WS_CURSOR   401152
#define WS_BSUM     801280
#define WS_PAIRS    801792
#define WS_AGG      13601792                 // pairs + 12.8 MB
#define WS_NEED_SPLIT 39201792ULL            // agg + 25.6 MB
#define WS_ZERO_BYTES 401152

// ---------------- 1) histogram of dst (4 edges/thread) ----------------
__global__ __launch_bounds__(256) void hist_kernel(
    const int* __restrict__ ei, int* __restrict__ rowstart)
{
    int e0 = (blockIdx.x * 256 + threadIdx.x) * 4;
    if (e0 >= N_EDGES) return;
    int4 d4 = *(const int4*)(ei + N_EDGES + e0);
    atomicAdd(&rowstart[1 + d4.x], 1);
    atomicAdd(&rowstart[1 + d4.y], 1);
    atomicAdd(&rowstart[1 + d4.z], 1);
    atomicAdd(&rowstart[1 + d4.w], 1);
}

// ---------------- 2a) per-block reduce of counts ----------------
__global__ __launch_bounds__(256) void scan1_kernel(
    const int* __restrict__ rowstart, int* __restrict__ bsum)
{
    __shared__ int red[256];
    const int t = threadIdx.x;
    const int base = blockIdx.x * S1_EPB + t * 4;
    int s = 0;
    #pragma unroll
    for (int k = 0; k < 4; ++k) {
        int idx = base + k;
        if (idx < SCAN_ELEMS) s += rowstart[idx];
    }
    red[t] = s;
    __syncthreads();
    for (int off = 128; off > 0; off >>= 1) {
        if (t < off) red[t] += red[t + off];
        __syncthreads();
    }
    if (t == 0) bsum[blockIdx.x] = red[0];
}

// ---------------- 2b) exclusive scan of block sums ----------------
__global__ __launch_bounds__(128) void scan2_kernel(int* __restrict__ bsum)
{
    __shared__ int buf[128];
    const int t = threadIdx.x;
    buf[t] = (t < S1_BLOCKS) ? bsum[t] : 0;
    __syncthreads();
    for (int off = 1; off < 128; off <<= 1) {
        int v = (t >= off) ? buf[t - off] : 0;
        __syncthreads();
        buf[t] += v;
        __syncthreads();
    }
    if (t < S1_BLOCKS) bsum[t] = (t > 0) ? buf[t - 1] : 0;
}

// ---------------- 2c) block-local inclusive scan + offset ----------------
__global__ __launch_bounds__(256) void scan3_kernel(
    int* __restrict__ rowstart, int* __restrict__ cursor,
    const int* __restrict__ bsum)
{
    __shared__ int tsum[256];
    const int t = threadIdx.x;
    const int base = blockIdx.x * S1_EPB + t * 4;
    int c0 = 0, c1 = 0, c2 = 0, c3 = 0;
    if (base + 0 < SCAN_ELEMS) c0 = rowstart[base + 0];
    if (base + 1 < SCAN_ELEMS) c1 = rowstart[base + 1];
    if (base + 2 < SCAN_ELEMS) c2 = rowstart[base + 2];
    if (base + 3 < SCAN_ELEMS) c3 = rowstart[base + 3];
    const int i0 = c0, i1 = i0 + c1, i2 = i1 + c2, i3 = i2 + c3;
    tsum[t] = i3;
    __syncthreads();
    for (int off = 1; off < 256; off <<= 1) {
        int v = (t >= off) ? tsum[t - off] : 0;
        __syncthreads();
        tsum[t] += v;
        __syncthreads();
    }
    const int boff = bsum[blockIdx.x] + tsum[t] - i3;
    const int r0 = boff + i0, r1 = boff + i1, r2 = boff + i2, r3 = boff + i3;
    if (base + 0 < SCAN_ELEMS) rowstart[base + 0] = r0;
    if (base + 1 < SCAN_ELEMS) rowstart[base + 1] = r1;
    if (base + 2 < SCAN_ELEMS) rowstart[base + 2] = r2;
    if (base + 3 < SCAN_ELEMS) rowstart[base + 3] = r3;
    if (base + 0 < N_NODES) cursor[base + 0] = r0;
    if (base + 1 < N_NODES) cursor[base + 1] = r1;
    if (base + 2 < N_NODES) cursor[base + 2] = r2;
    if (base + 3 < N_NODES) cursor[base + 3] = r3;
}

// ---------------- 3) fill (src, w) pairs — XCD-confined scatter ----------------
#define F_GROUPS 8
#define F_RANGE  (N_NODES / F_GROUPS)     // 12500
#define F_STRIPE 8192
#define F_NSTRIPE ((N_EDGES + F_STRIPE - 1) / F_STRIPE)  // 196
__global__ __launch_bounds__(256) void fill_kernel(
    const int* __restrict__ ei, const float* __restrict__ ew,
    int* __restrict__ cursor, float2* __restrict__ pairs)
{
    const int g  = blockIdx.x & (F_GROUPS - 1);
    const int s  = blockIdx.x / F_GROUPS;
    const int lo = g * F_RANGE;
    const int hi = lo + F_RANGE;
    const int ebase = s * F_STRIPE;
    #pragma unroll
    for (int i = 0; i < F_STRIPE / 1024; ++i) {   // 8 iters of 4 edges/thread
        int e0 = ebase + (i * 256 + threadIdx.x) * 4;
        if (e0 >= N_EDGES) continue;
        int4 d4 = *(const int4*)(ei + N_EDGES + e0);
        bool mx = (d4.x >= lo) & (d4.x < hi);
        bool my = (d4.y >= lo) & (d4.y < hi);
        bool mz = (d4.z >= lo) & (d4.z < hi);
        bool mw = (d4.w >= lo) & (d4.w < hi);
        if (!(mx | my | mz | mw)) continue;
        int4   s4 = *(const int4*)(ei + e0);
        float4 w4 = *(const float4*)(ew + e0);
        if (mx) { int p = atomicAdd(&cursor[d4.x], 1); pairs[p] = make_float2(__int_as_float(s4.x), w4.x); }
        if (my) { int p = atomicAdd(&cursor[d4.y], 1); pairs[p] = make_float2(__int_as_float(s4.y), w4.y); }
        if (mz) { int p = atomicAdd(&cursor[d4.z], 1); pairs[p] = make_float2(__int_as_float(s4.z), w4.z); }
        if (mw) { int p = atomicAdd(&cursor[d4.w], 1); pairs[p] = make_float2(__int_as_float(s4.w), w4.w); }
    }
}

// ---------------- 4a) gather-only: agg[n] = sum w * x[src]  ----------------
#define G_NPW 5   // nodes per wave -> 5000 blocks
__global__ __launch_bounds__(256) void gather_kernel(
    const float* __restrict__ x,
    const int* __restrict__ rowstart,
    const float2* __restrict__ pairs,
    float* __restrict__ agg)
{
    const int tid  = threadIdx.x;
    const int lane = tid & 63;
    const int wid  = tid >> 6;
    const int node0 = (blockIdx.x * 4 + wid) * G_NPW;

    for (int r = 0; r < G_NPW; ++r) {
        const int n  = node0 + r;
        const int jb = rowstart[n];
        const int je = rowstart[n + 1];
        float accA = 0.f, accB = 0.f;
        for (int j0 = jb; j0 < je; j0 += 64) {
            const int cnt = min(64, je - j0);
            float2 p = (lane < cnt) ? pairs[j0 + lane] : make_float2(0.f, 0.f);
            int   psrc = __float_as_int(p.x);
            float pw   = p.y;
            const int nch = (cnt + 15) >> 4;
            for (int c = 0; c < nch; ++c) {
                const int base = c * 16;
                #pragma unroll
                for (int t = 0; t < 16; t += 2) {
                    int   sA = __shfl(psrc, base + t);
                    float wA = __shfl(pw,   base + t);
                    int   sB = __shfl(psrc, base + t + 1);
                    float wB = __shfl(pw,   base + t + 1);
                    accA += wA * x[(size_t)sA * IN_DIM + lane];
                    accB += wB * x[(size_t)sB * IN_DIM + lane];
                }
            }
        }
        agg[(size_t)n * IN_DIM + lane] = accA + accB;   // single coalesced store
    }
}

// ---------------- 4b) streaming GEMV: h = (agg + x) @ W1 + b1, + BN partials --
#define M_NPW 25   // nodes per wave -> 1000 blocks
__global__ __launch_bounds__(256) void gemv_kernel(
    const float* __restrict__ agg,
    const float* __restrict__ x,
    const float* __restrict__ W1,   // [64,128] row-major
    const float* __restrict__ b1,
    float* __restrict__ h,          // [N,128]
    float* __restrict__ gsum, float* __restrict__ gsum2)
{
    __shared__ float w1s[IN_DIM][EMB];     // 32 KB
    __shared__ float rowbuf[4][IN_DIM];
    __shared__ float red[4][2][EMB];

    const int tid  = threadIdx.x;
    const int lane = tid & 63;
    const int wid  = tid >> 6;
    const int lane64 = lane + 64;

    for (int i = tid; i < IN_DIM * EMB; i += 256)
        w1s[i >> 7][i & 127] = W1[i];
    const float bl0 = b1[lane], bl1 = b1[lane64];
    __syncthreads();

    float s0 = 0.f, s20 = 0.f, s1 = 0.f, s21 = 0.f;
    const int node0 = (blockIdx.x * 4 + wid) * M_NPW;

    for (int r = 0; r < M_NPW; ++r) {
        const int n = node0 + r;
        rowbuf[wid][lane] = agg[(size_t)n * IN_DIM + lane]
                          + x[(size_t)n * IN_DIM + lane];   // self term (1+eps)=1

        float a0 = bl0, a1 = bl1;
        const float4* rb4 = (const float4*)rowbuf[wid];
        #pragma unroll
        for (int kg = 0; kg < 16; ++kg) {
            float4 rv = rb4[kg];
            int k = kg * 4;
            a0 += rv.x * w1s[k][lane]   + rv.y * w1s[k+1][lane]
                + rv.z * w1s[k+2][lane] + rv.w * w1s[k+3][lane];
            a1 += rv.x * w1s[k][lane64]   + rv.y * w1s[k+1][lane64]
                + rv.z * w1s[k+2][lane64] + rv.w * w1s[k+3][lane64];
        }
        h[(size_t)n * EMB + lane]   = a0;
        h[(size_t)n * EMB + lane64] = a1;
        s0 += a0; s20 += a0 * a0;
        s1 += a1; s21 += a1 * a1;
    }

    red[wid][0][lane] = s0;  red[wid][0][lane64] = s1;
    red[wid][1][lane] = s20; red[wid][1][lane64] = s21;
    __syncthreads();
    if (tid < EMB) {
        float t0 = red[0][0][tid] + red[1][0][tid] + red[2][0][tid] + red[3][0][tid];
        float t1 = red[0][1][tid] + red[1][1][tid] + red[2][1][tid] + red[3][1][tid];
        atomicAdd(&gsum[tid],  t0);
        atomicAdd(&gsum2[tid], t1);
    }
}

// ---------------- 4-fallback) fused gather+GEMV (round-5 structure, fp32) ----
#define B1_NPW 5
__global__ __launch_bounds__(256) void mlp1_fused_kernel(
    const float* __restrict__ x,
    const int* __restrict__ rowstart,
    const float2* __restrict__ pairs,
    const float* __restrict__ W1,
    const float* __restrict__ b1,
    float* __restrict__ h,
    float* __restrict__ gsum, float* __restrict__ gsum2)
{
    __shared__ float w1s[IN_DIM][EMB];
    __shared__ float rowbuf[4][IN_DIM];
    __shared__ float red[4][2][EMB];

    const int tid  = threadIdx.x;
    const int lane = tid & 63;
    const int wid  = tid >> 6;
    const int lane64 = lane + 64;

    for (int i = tid; i < IN_DIM * EMB; i += 256)
        w1s[i >> 7][i & 127] = W1[i];
    const float bl0 = b1[lane], bl1 = b1[lane64];
    __syncthreads();

    float s0 = 0.f, s20 = 0.f, s1 = 0.f, s21 = 0.f;
    const int node0 = (blockIdx.x * 4 + wid) * B1_NPW;

    for (int r = 0; r < B1_NPW; ++r) {
        const int n  = node0 + r;
        const int jb = rowstart[n];
        const int je = rowstart[n + 1];
        float accA = x[(size_t)n * IN_DIM + lane];
        float accB = 0.f;
        for (int j0 = jb; j0 < je; j0 += 64) {
            const int cnt = min(64, je - j0);
            float2 p = (lane < cnt) ? pairs[j0 + lane] : make_float2(0.f, 0.f);
            int   psrc = __float_as_int(p.x);
            float pw   = p.y;
            const int nch = (cnt + 15) >> 4;
            for (int c = 0; c < nch; ++c) {
                const int base = c * 16;
                #pragma unroll
                for (int t = 0; t < 16; t += 2) {
                    int   sA = __shfl(psrc, base + t);
                    float wA = __shfl(pw,   base + t);
                    int   sB = __shfl(psrc, base + t + 1);
                    float wB = __shfl(pw,   base + t + 1);
                    accA += wA * x[(size_t)sA * IN_DIM + lane];
                    accB += wB * x[(size_t)sB * IN_DIM + lane];
                }
            }
        }
        rowbuf[wid][lane] = accA + accB;
        float a0 = bl0, a1 = bl1;
        const float4* rb4 = (const float4*)rowbuf[wid];
        #pragma unroll
        for (int kg = 0; kg < 16; ++kg) {
            float4 rv = rb4[kg];
            int k = kg * 4;
            a0 += rv.x * w1s[k][lane]   + rv.y * w1s[k+1][lane]
                + rv.z * w1s[k+2][lane] + rv.w * w1s[k+3][lane];
            a1 += rv.x * w1s[k][lane64]   + rv.y * w1s[k+1][lane64]
                + rv.z * w1s[k+2][lane64] + rv.w * w1s[k+3][lane64];
        }
        h[(size_t)n * EMB + lane]   = a0;
        h[(size_t)n * EMB + lane64] = a1;
        s0 += a0; s20 += a0 * a0;
        s1 += a1; s21 += a1 * a1;
    }

    red[wid][0][lane] = s0;  red[wid][0][lane64] = s1;
    red[wid][1][lane] = s20; red[wid][1][lane64] = s21;
    __syncthreads();
    if (tid < EMB) {
        float t0 = red[0][0][tid] + red[1][0][tid] + red[2][0][tid] + red[3][0][tid];
        float t1 = red[0][1][tid] + red[1][1][tid] + red[2][1][tid] + red[3][1][tid];
        atomicAdd(&gsum[tid],  t0);
        atomicAdd(&gsum2[tid], t1);
    }
}

// ---------------- 5) out = relu(BN(h)) @ W2 + b2, fp16 MFMA (in-place) --------
// r12 post-mortem: scalar-FMA mlp2 was LDS-issue-bound (6.4M ds_read_b128
// ~= 125 us). MFMA amortizes operand reads across the 16x16 tile: 4
// ds_read_b128 per wave per 16x128 A-panel; W2 B-frags persist in VGPRs.
// A-frag: lane: row=l&15, k=(l>>4)*8+i (8 contiguous). B-frag: col=l&15,
// k=(l>>4)*8+i. C: col=l&15, row=(l>>4)*4+reg  [m89-verified].
#define MR 32            // rows per iter
#define M2_ITERS 5
#define M2_ROWS (MR * M2_ITERS)   // 160 rows/block -> 625 blocks
typedef _Float16 half8_t __attribute__((ext_vector_type(8)));
typedef float floatx4 __attribute__((ext_vector_type(4)));

__global__ __launch_bounds__(256) void mlp2_kernel(
    float* __restrict__ hio,
    const float* __restrict__ gsum, const float* __restrict__ gsum2,
    const float* __restrict__ gamma, const float* __restrict__ beta,
    const float* __restrict__ W2,   // [128,128] row-major, fp32
    const float* __restrict__ b2)
{
    __shared__ _Float16 Ph[MR][136];     // fp16 P tile, padded (8.5 KB)
    __shared__ float abuf[EMB], bbuf[EMB];

    const int tid  = threadIdx.x;
    const int lane = tid & 63;
    const int wid  = tid >> 6;
    const int rg   = wid >> 1;          // row group 0/1 (16 rows each)
    const int ch   = wid & 1;           // col half 0/1 (64 cols each)
    const int c0w  = ch * 64;
    const int l15  = lane & 15;
    const int kb   = lane >> 4;

    if (tid < EMB) {
        const float invN = 1.0f / (float)N_NODES;
        float mean = gsum[tid] * invN;
        float var  = gsum2[tid] * invN - mean * mean;
        float inv  = rsqrtf(var + BN_EPS);
        float a    = gamma[tid] * inv;
        abuf[tid] = a;
        bbuf[tid] = beta[tid] - mean * a;
    }

    // B-frags: 4 col-tiles x 4 k-chunks, fp16, held in VGPRs (64 regs)
    const int bcol = c0w + l15;
    half8_t Bf[4][4];
    #pragma unroll
    for (int ct = 0; ct < 4; ++ct) {
        #pragma unroll
        for (int kc = 0; kc < 4; ++kc) {
            #pragma unroll
            for (int i = 0; i < 8; ++i)
                Bf[ct][kc][i] = (_Float16)W2[(kc * 32 + kb * 8 + i) * EMB + ct * 16 + bcol];
        }
    }
    float b2c[4];
    #pragma unroll
    for (int ct = 0; ct < 4; ++ct) b2c[ct] = b2[ct * 16 + bcol];

    __syncthreads();   // abuf/bbuf ready

    const int r0blk = blockIdx.x * M2_ROWS;
    for (int it = 0; it < M2_ITERS; ++it) {
        const int r0 = r0blk + it * MR;
        // stage P = relu(BN(h)) rows r0..r0+31 as fp16 (coalesced float2 reads)
        #pragma unroll
        for (int i = 0; i < 8; ++i) {
            int j   = i * 256 + tid;      // 0..2047 half2-units
            int row = j >> 6;
            int c2  = (j & 63) * 2;
            const float2 hv = *(const float2*)&hio[(size_t)(r0 + row) * EMB + c2];
            float p0 = fmaxf(hv.x * abuf[c2]     + bbuf[c2],     0.f);
            float p1 = fmaxf(hv.y * abuf[c2 + 1] + bbuf[c2 + 1], 0.f);
            Ph[row][c2]     = (_Float16)p0;
            Ph[row][c2 + 1] = (_Float16)p1;
        }
        __syncthreads();   // Ph ready

        floatx4 acc[4];
        #pragma unroll
        for (int ct = 0; ct < 4; ++ct)
            acc[ct] = (floatx4){b2c[ct], b2c[ct], b2c[ct], b2c[ct]};
        #pragma unroll
        for (int kc = 0; kc < 4; ++kc) {
            half8_t af = *(half8_t*)&Ph[rg * 16 + l15][kc * 32 + kb * 8];
            #pragma unroll
            for (int ct = 0; ct < 4; ++ct)
                acc[ct] = __builtin_amdgcn_mfma_f32_16x16x32_f16(af, Bf[ct][kc], acc[ct], 0, 0, 0);
        }
        __syncthreads();   // all Ph reads done before next-iter staging

        #pragma unroll
        for (int ct = 0; ct < 4; ++ct) {
            #pragma unroll
            for (int i = 0; i < 4; ++i) {
                int row = r0 + rg * 16 + kb * 4 + i;
                hio[(size_t)row * EMB + c0w + ct * 16 + l15] = acc[ct][i];
            }
        }
    }
}

extern "C" void kernel_launch(void* const* d_in, const int* in_sizes, int n_in,
                              void* d_out, int out_size, void* d_ws, size_t ws_size,
                              hipStream_t stream)
{
    const float* x     = (const float*)d_in[0];
    const int*   ei    = (const int*)d_in[1];   // int32 [2,E]
    const float* ew    = (const float*)d_in[3];
    const float* W1    = (const float*)d_in[4];
    const float* b1    = (const float*)d_in[5];
    const float* gamma = (const float*)d_in[6];
    const float* beta  = (const float*)d_in[7];
    const float* W2    = (const float*)d_in[8];
    const float* b2    = (const float*)d_in[9];

    char* ws = (char*)d_ws;
    int*    rowstart = (int*)(ws + WS_ROWSTART);
    int*    cursor   = (int*)(ws + WS_CURSOR);
    float*  gsum     = (float*)(ws + WS_GSUM);
    float*  gsum2    = (float*)(ws + WS_GSUM2);
    int*    bsum     = (int*)(ws + WS_BSUM);
    float2* pairs    = (float2*)(ws + WS_PAIRS);
    float*  agg      = (float*)(ws + WS_AGG);
    float*  h        = (float*)d_out;

    const bool split = (ws_size >= WS_NEED_SPLIT);

    hipMemsetAsync(d_ws, 0, WS_ZERO_BYTES, stream);

    hist_kernel<<<(N_EDGES / 4 + 255) / 256, 256, 0, stream>>>(ei, rowstart);
    scan1_kernel<<<S1_BLOCKS, 256, 0, stream>>>(rowstart, bsum);
    scan2_kernel<<<1, 128, 0, stream>>>(bsum);
    scan3_kernel<<<S1_BLOCKS, 256, 0, stream>>>(rowstart, cursor, bsum);
    fill_kernel<<<F_NSTRIPE * F_GROUPS, 256, 0, stream>>>(ei, ew, cursor, pairs);
    if (split) {
        gather_kernel<<<N_NODES / (4 * G_NPW), 256, 0, stream>>>(x, rowstart, pairs, agg);
        gemv_kernel<<<N_NODES / (4 * M_NPW), 256, 0, stream>>>(agg, x, W1, b1, h, gsum, gsum2);
    } else {
        mlp1_fused_kernel<<<N_NODES / (4 * B1_NPW), 256, 0, stream>>>(
            x, rowstart, pairs, W1, b1, h, gsum, gsum2);
    }
    mlp2_kernel<<<N_NODES / M2_ROWS, 256, 0, stream>>>(h, gsum, gsum2, gamma, beta, W2, b2);
}

// Round 14
// 223.482 us; speedup vs baseline: 3.6964x; 1.3553x over previous
//
#include <hip/hip_runtime.h>

#define N_NODES 100000
#define IN_DIM 64
#define EMB 128
#define N_EDGES 1600000
#define BN_EPS 1e-5f

#define SCAN_ELEMS (N_NODES + 1)        // 100001
#define S1_EPB 1024
#define S1_BLOCKS ((SCAN_ELEMS + S1_EPB - 1) / S1_EPB)   // 98

// bucket partition
#define NB 98                 // buckets of 1024 dst each
#define BCAP 18432            // mean 16.3K + 16 sigma
#define FA_EPT 8
#define FA_BLK 2048           // 256 threads * 8 edges
#define FA_GRID ((N_EDGES + FA_BLK - 1) / FA_BLK)   // 782

// ---- workspace layout (bytes) ----
#define WS_ROWSTART 0
#define WS_GSUM     400128
#define WS_GSUM2    400640
#define WS_BSUM     401152
#define WS_BCUR     401664
#define WS_CURSOR   402176                  // fallback path only
#define WS_PAIRS    802304                  // 12.8 MB
#define WS_AGG      13602304                // 25.6 MB
#define WS_DSTARR   39202304                // 98*18432*4 = 7,225,344
#define WS_SWARR    46427648                // 98*18432*8 = 14,450,688
#define WS_NEED_SPLIT  39202304ULL
#define WS_NEED_BUCKET 60878336ULL
#define WS_ZERO_BYTES 402176

// ---------------- fillA: partition edges into 98 dst-buckets ----------------
// Block-local LDS counts -> one run reservation per block per bucket -> writes
// land in ~21-edge block-exclusive runs (L2-assembled full lines).
__global__ __launch_bounds__(256) void fillA_kernel(
    const int* __restrict__ ei, const float* __restrict__ ew,
    int* __restrict__ bcur, int* __restrict__ dstArr, float2* __restrict__ swArr)
{
    __shared__ int cnt[NB], base[NB];
    const int tid = threadIdx.x;
    if (tid < NB) cnt[tid] = 0;
    __syncthreads();
    const int e0 = blockIdx.x * FA_BLK;
    int pk[FA_EPT];
    #pragma unroll
    for (int i = 0; i < FA_EPT; ++i) {
        int e = e0 + i * 256 + tid;
        pk[i] = -1;
        if (e < N_EDGES) {
            int d = ei[N_EDGES + e];
            int b = d >> 10;
            int pos = atomicAdd(&cnt[b], 1);   // LDS atomic
            pk[i] = (b << 12) | pos;           // pos < 2048 fits 12 bits
        }
    }
    __syncthreads();
    if (tid < NB) base[tid] = atomicAdd(&bcur[tid], cnt[tid]);   // 98 global atomics/block
    __syncthreads();
    #pragma unroll
    for (int i = 0; i < FA_EPT; ++i) {
        int e = e0 + i * 256 + tid;
        if (pk[i] >= 0) {
            int b = pk[i] >> 12, pos = pk[i] & 0xFFF;
            int idx = b * BCAP + base[b] + pos;
            dstArr[idx] = ei[N_EDGES + e];
            swArr[idx]  = make_float2(__int_as_float(ei[e]), ew[e]);
        }
    }
}

// ---------------- histB: per-bucket LDS counting -> rowstart (no global atomics)
__global__ __launch_bounds__(1024) void histB_kernel(
    const int* __restrict__ bcur, const int* __restrict__ dstArr,
    int* __restrict__ rowstart)
{
    __shared__ int cnt2[1024];
    const int g = blockIdx.x;
    const int tid = threadIdx.x;
    cnt2[tid] = 0;
    __syncthreads();
    const int nE = bcur[g];
    const int* seg = dstArr + g * BCAP;
    for (int j = tid; j < nE; j += 1024)
        atomicAdd(&cnt2[seg[j] & 1023], 1);   // LDS atomic
    __syncthreads();
    int node = g * 1024 + tid;
    if (node < N_NODES) rowstart[1 + node] = cnt2[tid];
}

// ---------------- fillB: LDS-cursor scatter into block-owned pairs window ----
__global__ __launch_bounds__(1024) void fillB_kernel(
    const int* __restrict__ bcur, const int* __restrict__ dstArr,
    const float2* __restrict__ swArr, const int* __restrict__ rowstart,
    float2* __restrict__ pairs)
{
    __shared__ int csr[1024];
    const int g = blockIdx.x;
    const int tid = threadIdx.x;
    int node = g * 1024 + tid;
    csr[tid] = (node < N_NODES) ? rowstart[node] : 0;
    __syncthreads();
    const int nE = bcur[g];
    const int base = g * BCAP;
    #pragma unroll 4
    for (int j = tid; j < nE; j += 1024) {
        int d = dstArr[base + j];
        int p = atomicAdd(&csr[d & 1023], 1);   // LDS atomic, block-owned range
        pairs[p] = swArr[base + j];
    }
}

// ---------------- fallback: histogram of dst (4 edges/thread) ----------------
__global__ __launch_bounds__(256) void hist_kernel(
    const int* __restrict__ ei, int* __restrict__ rowstart)
{
    int e0 = (blockIdx.x * 256 + threadIdx.x) * 4;
    if (e0 >= N_EDGES) return;
    int4 d4 = *(const int4*)(ei + N_EDGES + e0);
    atomicAdd(&rowstart[1 + d4.x], 1);
    atomicAdd(&rowstart[1 + d4.y], 1);
    atomicAdd(&rowstart[1 + d4.z], 1);
    atomicAdd(&rowstart[1 + d4.w], 1);
}

// ---------------- fallback: fill (src, w) pairs (4 edges/thread) ----------------
__global__ __launch_bounds__(256) void fill_kernel(
    const int* __restrict__ ei, const float* __restrict__ ew,
    int* __restrict__ cursor, float2* __restrict__ pairs)
{
    int e0 = (blockIdx.x * 256 + threadIdx.x) * 4;
    if (e0 >= N_EDGES) return;
    int4   s4 = *(const int4*)(ei + e0);
    int4   d4 = *(const int4*)(ei + N_EDGES + e0);
    float4 w4 = *(const float4*)(ew + e0);
    int p0 = atomicAdd(&cursor[d4.x], 1);
    int p1 = atomicAdd(&cursor[d4.y], 1);
    int p2 = atomicAdd(&cursor[d4.z], 1);
    int p3 = atomicAdd(&cursor[d4.w], 1);
    pairs[p0] = make_float2(__int_as_float(s4.x), w4.x);
    pairs[p1] = make_float2(__int_as_float(s4.y), w4.y);
    pairs[p2] = make_float2(__int_as_float(s4.z), w4.z);
    pairs[p3] = make_float2(__int_as_float(s4.w), w4.w);
}

// ---------------- 2a) per-block reduce of counts ----------------
__global__ __launch_bounds__(256) void scan1_kernel(
    const int* __restrict__ rowstart, int* __restrict__ bsum)
{
    __shared__ int red[256];
    const int t = threadIdx.x;
    const int base = blockIdx.x * S1_EPB + t * 4;
    int s = 0;
    #pragma unroll
    for (int k = 0; k < 4; ++k) {
        int idx = base + k;
        if (idx < SCAN_ELEMS) s += rowstart[idx];
    }
    red[t] = s;
    __syncthreads();
    for (int off = 128; off > 0; off >>= 1) {
        if (t < off) red[t] += red[t + off];
        __syncthreads();
    }
    if (t == 0) bsum[blockIdx.x] = red[0];
}

// ---------------- 2b) exclusive scan of block sums ----------------
__global__ __launch_bounds__(128) void scan2_kernel(int* __restrict__ bsum)
{
    __shared__ int buf[128];
    const int t = threadIdx.x;
    buf[t] = (t < S1_BLOCKS) ? bsum[t] : 0;
    __syncthreads();
    for (int off = 1; off < 128; off <<= 1) {
        int v = (t >= off) ? buf[t - off] : 0;
        __syncthreads();
        buf[t] += v;
        __syncthreads();
    }
    if (t < S1_BLOCKS) bsum[t] = (t > 0) ? buf[t - 1] : 0;
}

// ---------------- 2c) block-local inclusive scan + offset ----------------
__global__ __launch_bounds__(256) void scan3_kernel(
    int* __restrict__ rowstart, int* __restrict__ cursor,
    const int* __restrict__ bsum)
{
    __shared__ int tsum[256];
    const int t = threadIdx.x;
    const int base = blockIdx.x * S1_EPB + t * 4;
    int c0 = 0, c1 = 0, c2 = 0, c3 = 0;
    if (base + 0 < SCAN_ELEMS) c0 = rowstart[base + 0];
    if (base + 1 < SCAN_ELEMS) c1 = rowstart[base + 1];
    if (base + 2 < SCAN_ELEMS) c2 = rowstart[base + 2];
    if (base + 3 < SCAN_ELEMS) c3 = rowstart[base + 3];
    const int i0 = c0, i1 = i0 + c1, i2 = i1 + c2, i3 = i2 + c3;
    tsum[t] = i3;
    __syncthreads();
    for (int off = 1; off < 256; off <<= 1) {
        int v = (t >= off) ? tsum[t - off] : 0;
        __syncthreads();
        tsum[t] += v;
        __syncthreads();
    }
    const int boff = bsum[blockIdx.x] + tsum[t] - i3;
    const int r0 = boff + i0, r1 = boff + i1, r2 = boff + i2, r3 = boff + i3;
    if (base + 0 < SCAN_ELEMS) rowstart[base + 0] = r0;
    if (base + 1 < SCAN_ELEMS) rowstart[base + 1] = r1;
    if (base + 2 < SCAN_ELEMS) rowstart[base + 2] = r2;
    if (base + 3 < SCAN_ELEMS) rowstart[base + 3] = r3;
    if (base + 0 < N_NODES) cursor[base + 0] = r0;
    if (base + 1 < N_NODES) cursor[base + 1] = r1;
    if (base + 2 < N_NODES) cursor[base + 2] = r2;
    if (base + 3 < N_NODES) cursor[base + 3] = r3;
}

// ---------------- gather-only: agg[n] = sum w * x[src]  ----------------
#define G_NPW 5   // nodes per wave -> 5000 blocks
__global__ __launch_bounds__(256) void gather_kernel(
    const float* __restrict__ x,
    const int* __restrict__ rowstart,
    const float2* __restrict__ pairs,
    float* __restrict__ agg)
{
    const int tid  = threadIdx.x;
    const int lane = tid & 63;
    const int wid  = tid >> 6;
    const int node0 = (blockIdx.x * 4 + wid) * G_NPW;

    for (int r = 0; r < G_NPW; ++r) {
        const int n  = node0 + r;
        const int jb = rowstart[n];
        const int je = rowstart[n + 1];
        float accA = 0.f, accB = 0.f;
        for (int j0 = jb; j0 < je; j0 += 64) {
            const int cnt = min(64, je - j0);
            float2 p = (lane < cnt) ? pairs[j0 + lane] : make_float2(0.f, 0.f);
            int   psrc = __float_as_int(p.x);
            float pw   = p.y;
            const int nch = (cnt + 15) >> 4;
            for (int c = 0; c < nch; ++c) {
                const int base = c * 16;
                #pragma unroll
                for (int t = 0; t < 16; t += 2) {
                    int   sA = __shfl(psrc, base + t);
                    float wA = __shfl(pw,   base + t);
                    int   sB = __shfl(psrc, base + t + 1);
                    float wB = __shfl(pw,   base + t + 1);
                    accA += wA * x[(size_t)sA * IN_DIM + lane];
                    accB += wB * x[(size_t)sB * IN_DIM + lane];
                }
            }
        }
        agg[(size_t)n * IN_DIM + lane] = accA + accB;
    }
}

// ---------------- streaming GEMV: h = (agg + x) @ W1 + b1, + BN partials --
#define M_NPW 25   // nodes per wave -> 1000 blocks
__global__ __launch_bounds__(256) void gemv_kernel(
    const float* __restrict__ agg,
    const float* __restrict__ x,
    const float* __restrict__ W1,   // [64,128] row-major
    const float* __restrict__ b1,
    float* __restrict__ h,          // [N,128]
    float* __restrict__ gsum, float* __restrict__ gsum2)
{
    __shared__ float w1s[IN_DIM][EMB];
    __shared__ float rowbuf[4][IN_DIM];
    __shared__ float red[4][2][EMB];

    const int tid  = threadIdx.x;
    const int lane = tid & 63;
    const int wid  = tid >> 6;
    const int lane64 = lane + 64;

    for (int i = tid; i < IN_DIM * EMB; i += 256)
        w1s[i >> 7][i & 127] = W1[i];
    const float bl0 = b1[lane], bl1 = b1[lane64];
    __syncthreads();

    float s0 = 0.f, s20 = 0.f, s1 = 0.f, s21 = 0.f;
    const int node0 = (blockIdx.x * 4 + wid) * M_NPW;

    for (int r = 0; r < M_NPW; ++r) {
        const int n = node0 + r;
        rowbuf[wid][lane] = agg[(size_t)n * IN_DIM + lane]
                          + x[(size_t)n * IN_DIM + lane];

        float a0 = bl0, a1 = bl1;
        const float4* rb4 = (const float4*)rowbuf[wid];
        #pragma unroll
        for (int kg = 0; kg < 16; ++kg) {
            float4 rv = rb4[kg];
            int k = kg * 4;
            a0 += rv.x * w1s[k][lane]   + rv.y * w1s[k+1][lane]
                + rv.z * w1s[k+2][lane] + rv.w * w1s[k+3][lane];
            a1 += rv.x * w1s[k][lane64]   + rv.y * w1s[k+1][lane64]
                + rv.z * w1s[k+2][lane64] + rv.w * w1s[k+3][lane64];
        }
        h[(size_t)n * EMB + lane]   = a0;
        h[(size_t)n * EMB + lane64] = a1;
        s0 += a0; s20 += a0 * a0;
        s1 += a1; s21 += a1 * a1;
    }

    red[wid][0][lane] = s0;  red[wid][0][lane64] = s1;
    red[wid][1][lane] = s20; red[wid][1][lane64] = s21;
    __syncthreads();
    if (tid < EMB) {
        float t0 = red[0][0][tid] + red[1][0][tid] + red[2][0][tid] + red[3][0][tid];
        float t1 = red[0][1][tid] + red[1][1][tid] + red[2][1][tid] + red[3][1][tid];
        atomicAdd(&gsum[tid],  t0);
        atomicAdd(&gsum2[tid], t1);
    }
}

// ---------------- out = relu(BN(h)) @ W2 + b2, fp16 MFMA (in-place) --------
#define MR 32
#define M2_ITERS 5
#define M2_ROWS (MR * M2_ITERS)   // 160 rows/block -> 625 blocks
typedef _Float16 half8_t __attribute__((ext_vector_type(8)));
typedef float floatx4 __attribute__((ext_vector_type(4)));

__global__ __launch_bounds__(256) void mlp2_kernel(
    float* __restrict__ hio,
    const float* __restrict__ gsum, const float* __restrict__ gsum2,
    const float* __restrict__ gamma, const float* __restrict__ beta,
    const float* __restrict__ W2,   // [128,128] row-major, fp32
    const float* __restrict__ b2)
{
    __shared__ _Float16 Ph[MR][136];
    __shared__ float abuf[EMB], bbuf[EMB];

    const int tid  = threadIdx.x;
    const int lane = tid & 63;
    const int wid  = tid >> 6;
    const int rg   = wid >> 1;
    const int ch   = wid & 1;
    const int c0w  = ch * 64;
    const int l15  = lane & 15;
    const int kb   = lane >> 4;

    if (tid < EMB) {
        const float invN = 1.0f / (float)N_NODES;
        float mean = gsum[tid] * invN;
        float var  = gsum2[tid] * invN - mean * mean;
        float inv  = rsqrtf(var + BN_EPS);
        float a    = gamma[tid] * inv;
        abuf[tid] = a;
        bbuf[tid] = beta[tid] - mean * a;
    }

    const int bcol = c0w + l15;
    half8_t Bf[4][4];
    #pragma unroll
    for (int ct = 0; ct < 4; ++ct) {
        #pragma unroll
        for (int kc = 0; kc < 4; ++kc) {
            #pragma unroll
            for (int i = 0; i < 8; ++i)
                Bf[ct][kc][i] = (_Float16)W2[(kc * 32 + kb * 8 + i) * EMB + ct * 16 + bcol];
        }
    }
    float b2c[4];
    #pragma unroll
    for (int ct = 0; ct < 4; ++ct) b2c[ct] = b2[ct * 16 + bcol];

    __syncthreads();

    const int r0blk = blockIdx.x * M2_ROWS;
    for (int it = 0; it < M2_ITERS; ++it) {
        const int r0 = r0blk + it * MR;
        #pragma unroll
        for (int i = 0; i < 8; ++i) {
            int j   = i * 256 + tid;
            int row = j >> 6;
            int c2  = (j & 63) * 2;
            const float2 hv = *(const float2*)&hio[(size_t)(r0 + row) * EMB + c2];
            float p0 = fmaxf(hv.x * abuf[c2]     + bbuf[c2],     0.f);
            float p1 = fmaxf(hv.y * abuf[c2 + 1] + bbuf[c2 + 1], 0.f);
            Ph[row][c2]     = (_Float16)p0;
            Ph[row][c2 + 1] = (_Float16)p1;
        }
        __syncthreads();

        floatx4 acc[4];
        #pragma unroll
        for (int ct = 0; ct < 4; ++ct)
            acc[ct] = (floatx4){b2c[ct], b2c[ct], b2c[ct], b2c[ct]};
        #pragma unroll
        for (int kc = 0; kc < 4; ++kc) {
            half8_t af = *(half8_t*)&Ph[rg * 16 + l15][kc * 32 + kb * 8];
            #pragma unroll
            for (int ct = 0; ct < 4; ++ct)
                acc[ct] = __builtin_amdgcn_mfma_f32_16x16x32_f16(af, Bf[ct][kc], acc[ct], 0, 0, 0);
        }
        __syncthreads();

        #pragma unroll
        for (int ct = 0; ct < 4; ++ct) {
            #pragma unroll
            for (int i = 0; i < 4; ++i) {
                int row = r0 + rg * 16 + kb * 4 + i;
                hio[(size_t)row * EMB + c0w + ct * 16 + l15] = acc[ct][i];
            }
        }
    }
}

extern "C" void kernel_launch(void* const* d_in, const int* in_sizes, int n_in,
                              void* d_out, int out_size, void* d_ws, size_t ws_size,
                              hipStream_t stream)
{
    const float* x     = (const float*)d_in[0];
    const int*   ei    = (const int*)d_in[1];   // int32 [2,E]
    const float* ew    = (const float*)d_in[3];
    const float* W1    = (const float*)d_in[4];
    const float* b1    = (const float*)d_in[5];
    const float* gamma = (const float*)d_in[6];
    const float* beta  = (const float*)d_in[7];
    const float* W2    = (const float*)d_in[8];
    const float* b2    = (const float*)d_in[9];

    char* ws = (char*)d_ws;
    int*    rowstart = (int*)(ws + WS_ROWSTART);
    float*  gsum     = (float*)(ws + WS_GSUM);
    float*  gsum2    = (float*)(ws + WS_GSUM2);
    int*    bsum     = (int*)(ws + WS_BSUM);
    int*    bcur     = (int*)(ws + WS_BCUR);
    int*    cursor   = (int*)(ws + WS_CURSOR);
    float2* pairs    = (float2*)(ws + WS_PAIRS);
    float*  agg      = (float*)(ws + WS_AGG);
    int*    dstArr   = (int*)(ws + WS_DSTARR);
    float2* swArr    = (float2*)(ws + WS_SWARR);
    float*  h        = (float*)d_out;

    const bool bucket = (ws_size >= WS_NEED_BUCKET);

    hipMemsetAsync(d_ws, 0, WS_ZERO_BYTES, stream);

    if (bucket) {
        fillA_kernel<<<FA_GRID, 256, 0, stream>>>(ei, ew, bcur, dstArr, swArr);
        histB_kernel<<<NB, 1024, 0, stream>>>(bcur, dstArr, rowstart);
        scan1_kernel<<<S1_BLOCKS, 256, 0, stream>>>(rowstart, bsum);
        scan2_kernel<<<1, 128, 0, stream>>>(bsum);
        scan3_kernel<<<S1_BLOCKS, 256, 0, stream>>>(rowstart, cursor, bsum);
        fillB_kernel<<<NB, 1024, 0, stream>>>(bcur, dstArr, swArr, rowstart, pairs);
    } else {
        hist_kernel<<<(N_EDGES / 4 + 255) / 256, 256, 0, stream>>>(ei, rowstart);
        scan1_kernel<<<S1_BLOCKS, 256, 0, stream>>>(rowstart, bsum);
        scan2_kernel<<<1, 128, 0, stream>>>(bsum);
        scan3_kernel<<<S1_BLOCKS, 256, 0, stream>>>(rowstart, cursor, bsum);
        fill_kernel<<<(N_EDGES / 4 + 255) / 256, 256, 0, stream>>>(ei, ew, cursor, pairs);
    }
    gather_kernel<<<N_NODES / (4 * G_NPW), 256, 0, stream>>>(x, rowstart, pairs, agg);
    gemv_kernel<<<N_NODES / (4 * M_NPW), 256, 0, stream>>>(agg, x, W1, b1, h, gsum, gsum2);
    mlp2_kernel<<<N_NODES / M2_ROWS, 256, 0, stream>>>(h, gsum, gsum2, gamma, beta, W2, b2);
}

// Round 15
// 197.078 us; speedup vs baseline: 4.1916x; 1.1340x over previous
//
#include <hip/hip_runtime.h>

#define N_NODES 100000
#define IN_DIM 64
#define EMB 128
#define N_EDGES 1600000
#define BN_EPS 1e-5f

#define SCAN_ELEMS (N_NODES + 1)        // 100001
#define S1_EPB 1024
#define S1_BLOCKS ((SCAN_ELEMS + S1_EPB - 1) / S1_EPB)   // 98

// bucket partition
#define NB 98                 // buckets of 1024 dst each
#define BCAP 18432
#define FA_EPT 8
#define FA_BLK 2048
#define FA_GRID ((N_EDGES + FA_BLK - 1) / FA_BLK)   // 782

// ---- workspace layout (bytes) ----
#define WS_ROWSTART 0
#define WS_GSUM     400128
#define WS_GSUM2    400640
#define WS_BSUM     401152
#define WS_BCUR     401664
#define WS_CURSOR   402176
#define WS_PAIRS    802304                  // 12.8 MB
#define WS_AGG      13602304                // 25.6 MB
#define WS_DSTARR   39202304                // 7.2 MB
#define WS_SWARR    46427648                // 14.5 MB
#define WS_NEED_BUCKET 60878336ULL
#define WS_ZERO_BYTES 402176

typedef _Float16 half8_t __attribute__((ext_vector_type(8)));
typedef float floatx4 __attribute__((ext_vector_type(4)));

// ---------------- fillA: partition edges into 98 dst-buckets ----------------
__global__ __launch_bounds__(256) void fillA_kernel(
    const int* __restrict__ ei, const float* __restrict__ ew,
    int* __restrict__ bcur, int* __restrict__ dstArr, float2* __restrict__ swArr)
{
    __shared__ int cnt[NB], base[NB];
    const int tid = threadIdx.x;
    if (tid < NB) cnt[tid] = 0;
    __syncthreads();
    const int e0 = blockIdx.x * FA_BLK;
    int pk[FA_EPT];
    #pragma unroll
    for (int i = 0; i < FA_EPT; ++i) {
        int e = e0 + i * 256 + tid;
        pk[i] = -1;
        if (e < N_EDGES) {
            int d = ei[N_EDGES + e];
            int b = d >> 10;
            int pos = atomicAdd(&cnt[b], 1);   // LDS atomic
            pk[i] = (b << 12) | pos;
        }
    }
    __syncthreads();
    if (tid < NB) base[tid] = atomicAdd(&bcur[tid], cnt[tid]);
    __syncthreads();
    #pragma unroll
    for (int i = 0; i < FA_EPT; ++i) {
        int e = e0 + i * 256 + tid;
        if (pk[i] >= 0) {
            int b = pk[i] >> 12, pos = pk[i] & 0xFFF;
            int idx = b * BCAP + base[b] + pos;
            dstArr[idx] = ei[N_EDGES + e];
            swArr[idx]  = make_float2(__int_as_float(ei[e]), ew[e]);
        }
    }
}

// ---------------- histB: per-bucket LDS counting -> rowstart ----------------
__global__ __launch_bounds__(1024) void histB_kernel(
    const int* __restrict__ bcur, const int* __restrict__ dstArr,
    int* __restrict__ rowstart)
{
    __shared__ int cnt2[1024];
    const int g = blockIdx.x;
    const int tid = threadIdx.x;
    cnt2[tid] = 0;
    __syncthreads();
    const int nE = bcur[g];
    const int* seg = dstArr + g * BCAP;
    for (int j = tid; j < nE; j += 1024)
        atomicAdd(&cnt2[seg[j] & 1023], 1);
    __syncthreads();
    int node = g * 1024 + tid;
    if (node < N_NODES) rowstart[1 + node] = cnt2[tid];
}

// ---------------- fillB: LDS-cursor scatter into block-owned window ----------
__global__ __launch_bounds__(1024) void fillB_kernel(
    const int* __restrict__ bcur, const int* __restrict__ dstArr,
    const float2* __restrict__ swArr, const int* __restrict__ rowstart,
    float2* __restrict__ pairs)
{
    __shared__ int csr[1024];
    const int g = blockIdx.x;
    const int tid = threadIdx.x;
    int node = g * 1024 + tid;
    csr[tid] = (node < N_NODES) ? rowstart[node] : 0;
    __syncthreads();
    const int nE = bcur[g];
    const int base = g * BCAP;
    #pragma unroll 4
    for (int j = tid; j < nE; j += 1024) {
        int d = dstArr[base + j];
        int p = atomicAdd(&csr[d & 1023], 1);
        pairs[p] = swArr[base + j];
    }
}

// ---------------- 2a) per-block reduce of counts ----------------
__global__ __launch_bounds__(256) void scan1_kernel(
    const int* __restrict__ rowstart, int* __restrict__ bsum)
{
    __shared__ int red[256];
    const int t = threadIdx.x;
    const int base = blockIdx.x * S1_EPB + t * 4;
    int s = 0;
    #pragma unroll
    for (int k = 0; k < 4; ++k) {
        int idx = base + k;
        if (idx < SCAN_ELEMS) s += rowstart[idx];
    }
    red[t] = s;
    __syncthreads();
    for (int off = 128; off > 0; off >>= 1) {
        if (t < off) red[t] += red[t + off];
        __syncthreads();
    }
    if (t == 0) bsum[blockIdx.x] = red[0];
}

// ---------------- 2b) exclusive scan of block sums ----------------
__global__ __launch_bounds__(128) void scan2_kernel(int* __restrict__ bsum)
{
    __shared__ int buf[128];
    const int t = threadIdx.x;
    buf[t] = (t < S1_BLOCKS) ? bsum[t] : 0;
    __syncthreads();
    for (int off = 1; off < 128; off <<= 1) {
        int v = (t >= off) ? buf[t - off] : 0;
        __syncthreads();
        buf[t] += v;
        __syncthreads();
    }
    if (t < S1_BLOCKS) bsum[t] = (t > 0) ? buf[t - 1] : 0;
}

// ---------------- 2c) block-local inclusive scan + offset ----------------
__global__ __launch_bounds__(256) void scan3_kernel(
    int* __restrict__ rowstart, int* __restrict__ cursor,
    const int* __restrict__ bsum)
{
    __shared__ int tsum[256];
    const int t = threadIdx.x;
    const int base = blockIdx.x * S1_EPB + t * 4;
    int c0 = 0, c1 = 0, c2 = 0, c3 = 0;
    if (base + 0 < SCAN_ELEMS) c0 = rowstart[base + 0];
    if (base + 1 < SCAN_ELEMS) c1 = rowstart[base + 1];
    if (base + 2 < SCAN_ELEMS) c2 = rowstart[base + 2];
    if (base + 3 < SCAN_ELEMS) c3 = rowstart[base + 3];
    const int i0 = c0, i1 = i0 + c1, i2 = i1 + c2, i3 = i2 + c3;
    tsum[t] = i3;
    __syncthreads();
    for (int off = 1; off < 256; off <<= 1) {
        int v = (t >= off) ? tsum[t - off] : 0;
        __syncthreads();
        tsum[t] += v;
        __syncthreads();
    }
    const int boff = bsum[blockIdx.x] + tsum[t] - i3;
    const int r0 = boff + i0, r1 = boff + i1, r2 = boff + i2, r3 = boff + i3;
    if (base + 0 < SCAN_ELEMS) rowstart[base + 0] = r0;
    if (base + 1 < SCAN_ELEMS) rowstart[base + 1] = r1;
    if (base + 2 < SCAN_ELEMS) rowstart[base + 2] = r2;
    if (base + 3 < SCAN_ELEMS) rowstart[base + 3] = r3;
    if (base + 0 < N_NODES) cursor[base + 0] = r0;
    if (base + 1 < N_NODES) cursor[base + 1] = r1;
    if (base + 2 < N_NODES) cursor[base + 2] = r2;
    if (base + 3 < N_NODES) cursor[base + 3] = r3;
}

// ---------------- gather-only: agg[n] = sum w * x[src]  ----------------
#define G_NPW 5
__global__ __launch_bounds__(256) void gather_kernel(
    const float* __restrict__ x,
    const int* __restrict__ rowstart,
    const float2* __restrict__ pairs,
    float* __restrict__ agg)
{
    const int tid  = threadIdx.x;
    const int lane = tid & 63;
    const int wid  = tid >> 6;
    const int node0 = (blockIdx.x * 4 + wid) * G_NPW;

    for (int r = 0; r < G_NPW; ++r) {
        const int n  = node0 + r;
        const int jb = rowstart[n];
        const int je = rowstart[n + 1];
        float accA = 0.f, accB = 0.f;
        for (int j0 = jb; j0 < je; j0 += 64) {
            const int cnt = min(64, je - j0);
            float2 p = (lane < cnt) ? pairs[j0 + lane] : make_float2(0.f, 0.f);
            int   psrc = __float_as_int(p.x);
            float pw   = p.y;
            const int nch = (cnt + 15) >> 4;
            for (int c = 0; c < nch; ++c) {
                const int base = c * 16;
                #pragma unroll
                for (int t = 0; t < 16; t += 2) {
                    int   sA = __shfl(psrc, base + t);
                    float wA = __shfl(pw,   base + t);
                    int   sB = __shfl(psrc, base + t + 1);
                    float wB = __shfl(pw,   base + t + 1);
                    accA += wA * x[(size_t)sA * IN_DIM + lane];
                    accB += wB * x[(size_t)sB * IN_DIM + lane];
                }
            }
        }
        agg[(size_t)n * IN_DIM + lane] = accA + accB;
    }
}

// ---------------- gemv (MFMA): h = (agg + x) @ W1 + b1, + BN partials --------
// r14 post-mortem: scalar GEMV was LDS-issue bound (128 ds_read_b32/row/thread,
// VALUBusy 38%, 70us). MFMA: A=32x64 fp16 tile in LDS, W1 B-frags in 32 VGPRs,
// 8 MFMA per 32-row tile. BN partials from C-frags (col fixed per lane).
#define GM_ITERS 5
#define GM_ROWS (32 * GM_ITERS)   // 160 rows/block -> 625 blocks
__global__ __launch_bounds__(256) void gemv_kernel(
    const float* __restrict__ agg,
    const float* __restrict__ x,
    const float* __restrict__ W1,   // [64,128] row-major, fp32
    const float* __restrict__ b1,
    float* __restrict__ h,          // [N,128]
    float* __restrict__ gsum, float* __restrict__ gsum2)
{
    __shared__ _Float16 Ah[32][72];      // fp16 A tile, 144 B row stride (16B-mult)
    __shared__ float redS[EMB], redQ[EMB];

    const int tid  = threadIdx.x;
    const int lane = tid & 63;
    const int wid  = tid >> 6;
    const int rg   = wid >> 1;          // row group 0/1
    const int ch   = wid & 1;           // col half 0/1
    const int c0w  = ch * 64;
    const int l15  = lane & 15;
    const int kb   = lane >> 4;

    // B-frags: 4 col-tiles x 2 k-chunks (K=64)
    half8_t Bf[4][2];
    #pragma unroll
    for (int ct = 0; ct < 4; ++ct)
        #pragma unroll
        for (int kc = 0; kc < 2; ++kc)
            #pragma unroll
            for (int i = 0; i < 8; ++i)
                Bf[ct][kc][i] = (_Float16)W1[(kc * 32 + kb * 8 + i) * EMB + ct * 16 + c0w + l15];
    float b1c[4];
    #pragma unroll
    for (int ct = 0; ct < 4; ++ct) b1c[ct] = b1[ct * 16 + c0w + l15];

    if (tid < EMB) { redS[tid] = 0.f; redQ[tid] = 0.f; }

    float sAcc[4] = {0.f, 0.f, 0.f, 0.f};
    float qAcc[4] = {0.f, 0.f, 0.f, 0.f};

    const int r0blk = blockIdx.x * GM_ROWS;
    for (int it = 0; it < GM_ITERS; ++it) {
        const int r0 = r0blk + it * 32;
        __syncthreads();   // prev-iter Ah reads done (and redS/redQ init on it=0)
        #pragma unroll
        for (int i = 0; i < 2; ++i) {
            int j   = i * 256 + tid;     // 0..511 float4 units
            int row = j >> 4;
            int c4  = (j & 15) * 4;
            float4 av = *(const float4*)&agg[(size_t)(r0 + row) * IN_DIM + c4];
            float4 xv = *(const float4*)&x[(size_t)(r0 + row) * IN_DIM + c4];
            Ah[row][c4 + 0] = (_Float16)(av.x + xv.x);
            Ah[row][c4 + 1] = (_Float16)(av.y + xv.y);
            Ah[row][c4 + 2] = (_Float16)(av.z + xv.z);
            Ah[row][c4 + 3] = (_Float16)(av.w + xv.w);
        }
        __syncthreads();   // Ah ready

        floatx4 acc[4];
        #pragma unroll
        for (int ct = 0; ct < 4; ++ct)
            acc[ct] = (floatx4){b1c[ct], b1c[ct], b1c[ct], b1c[ct]};
        #pragma unroll
        for (int kc = 0; kc < 2; ++kc) {
            half8_t af = *(half8_t*)&Ah[rg * 16 + l15][kc * 32 + kb * 8];
            #pragma unroll
            for (int ct = 0; ct < 4; ++ct)
                acc[ct] = __builtin_amdgcn_mfma_f32_16x16x32_f16(af, Bf[ct][kc], acc[ct], 0, 0, 0);
        }

        #pragma unroll
        for (int ct = 0; ct < 4; ++ct) {
            #pragma unroll
            for (int i = 0; i < 4; ++i) {
                int row = r0 + rg * 16 + kb * 4 + i;
                float v = acc[ct][i];
                h[(size_t)row * EMB + c0w + ct * 16 + l15] = v;
                sAcc[ct] += v;
                qAcc[ct] += v * v;
            }
        }
    }

    __syncthreads();
    #pragma unroll
    for (int ct = 0; ct < 4; ++ct) {
        atomicAdd(&redS[c0w + ct * 16 + l15], sAcc[ct]);   // LDS float atomics
        atomicAdd(&redQ[c0w + ct * 16 + l15], qAcc[ct]);
    }
    __syncthreads();
    if (tid < EMB) {
        atomicAdd(&gsum[tid],  redS[tid]);
        atomicAdd(&gsum2[tid], redQ[tid]);
    }
}

// ---------------- out = relu(BN(h)) @ W2 + b2, fp16 MFMA (in-place) --------
#define MR 32
#define M2_ITERS 5
#define M2_ROWS (MR * M2_ITERS)   // 160 rows/block -> 625 blocks

__global__ __launch_bounds__(256) void mlp2_kernel(
    float* __restrict__ hio,
    const float* __restrict__ gsum, const float* __restrict__ gsum2,
    const float* __restrict__ gamma, const float* __restrict__ beta,
    const float* __restrict__ W2,   // [128,128] row-major, fp32
    const float* __restrict__ b2)
{
    __shared__ _Float16 Ph[MR][136];
    __shared__ float abuf[EMB], bbuf[EMB];

    const int tid  = threadIdx.x;
    const int lane = tid & 63;
    const int wid  = tid >> 6;
    const int rg   = wid >> 1;
    const int ch   = wid & 1;
    const int c0w  = ch * 64;
    const int l15  = lane & 15;
    const int kb   = lane >> 4;

    if (tid < EMB) {
        const float invN = 1.0f / (float)N_NODES;
        float mean = gsum[tid] * invN;
        float var  = gsum2[tid] * invN - mean * mean;
        float inv  = rsqrtf(var + BN_EPS);
        float a    = gamma[tid] * inv;
        abuf[tid] = a;
        bbuf[tid] = beta[tid] - mean * a;
    }

    const int bcol = c0w + l15;
    half8_t Bf[4][4];
    #pragma unroll
    for (int ct = 0; ct < 4; ++ct) {
        #pragma unroll
        for (int kc = 0; kc < 4; ++kc) {
            #pragma unroll
            for (int i = 0; i < 8; ++i)
                Bf[ct][kc][i] = (_Float16)W2[(kc * 32 + kb * 8 + i) * EMB + ct * 16 + bcol];
        }
    }
    float b2c[4];
    #pragma unroll
    for (int ct = 0; ct < 4; ++ct) b2c[ct] = b2[ct * 16 + bcol];

    __syncthreads();

    const int r0blk = blockIdx.x * M2_ROWS;
    for (int it = 0; it < M2_ITERS; ++it) {
        const int r0 = r0blk + it * MR;
        #pragma unroll
        for (int i = 0; i < 8; ++i) {
            int j   = i * 256 + tid;
            int row = j >> 6;
            int c2  = (j & 63) * 2;
            const float2 hv = *(const float2*)&hio[(size_t)(r0 + row) * EMB + c2];
            float p0 = fmaxf(hv.x * abuf[c2]     + bbuf[c2],     0.f);
            float p1 = fmaxf(hv.y * abuf[c2 + 1] + bbuf[c2 + 1], 0.f);
            Ph[row][c2]     = (_Float16)p0;
            Ph[row][c2 + 1] = (_Float16)p1;
        }
        __syncthreads();

        floatx4 acc[4];
        #pragma unroll
        for (int ct = 0; ct < 4; ++ct)
            acc[ct] = (floatx4){b2c[ct], b2c[ct], b2c[ct], b2c[ct]};
        #pragma unroll
        for (int kc = 0; kc < 4; ++kc) {
            half8_t af = *(half8_t*)&Ph[rg * 16 + l15][kc * 32 + kb * 8];
            #pragma unroll
            for (int ct = 0; ct < 4; ++ct)
                acc[ct] = __builtin_amdgcn_mfma_f32_16x16x32_f16(af, Bf[ct][kc], acc[ct], 0, 0, 0);
        }
        __syncthreads();

        #pragma unroll
        for (int ct = 0; ct < 4; ++ct) {
            #pragma unroll
            for (int i = 0; i < 4; ++i) {
                int row = r0 + rg * 16 + kb * 4 + i;
                hio[(size_t)row * EMB + c0w + ct * 16 + l15] = acc[ct][i];
            }
        }
    }
}

extern "C" void kernel_launch(void* const* d_in, const int* in_sizes, int n_in,
                              void* d_out, int out_size, void* d_ws, size_t ws_size,
                              hipStream_t stream)
{
    const float* x     = (const float*)d_in[0];
    const int*   ei    = (const int*)d_in[1];   // int32 [2,E]
    const float* ew    = (const float*)d_in[3];
    const float* W1    = (const float*)d_in[4];
    const float* b1    = (const float*)d_in[5];
    const float* gamma = (const float*)d_in[6];
    const float* beta  = (const float*)d_in[7];
    const float* W2    = (const float*)d_in[8];
    const float* b2    = (const float*)d_in[9];

    char* ws = (char*)d_ws;
    int*    rowstart = (int*)(ws + WS_ROWSTART);
    float*  gsum     = (float*)(ws + WS_GSUM);
    float*  gsum2    = (float*)(ws + WS_GSUM2);
    int*    bsum     = (int*)(ws + WS_BSUM);
    int*    bcur     = (int*)(ws + WS_BCUR);
    int*    cursor   = (int*)(ws + WS_CURSOR);
    float2* pairs    = (float2*)(ws + WS_PAIRS);
    float*  agg      = (float*)(ws + WS_AGG);
    int*    dstArr   = (int*)(ws + WS_DSTARR);
    float2* swArr    = (float2*)(ws + WS_SWARR);
    float*  h        = (float*)d_out;

    hipMemsetAsync(d_ws, 0, WS_ZERO_BYTES, stream);

    fillA_kernel<<<FA_GRID, 256, 0, stream>>>(ei, ew, bcur, dstArr, swArr);
    histB_kernel<<<NB, 1024, 0, stream>>>(bcur, dstArr, rowstart);
    scan1_kernel<<<S1_BLOCKS, 256, 0, stream>>>(rowstart, bsum);
    scan2_kernel<<<1, 128, 0, stream>>>(bsum);
    scan3_kernel<<<S1_BLOCKS, 256, 0, stream>>>(rowstart, cursor, bsum);
    fillB_kernel<<<NB, 1024, 0, stream>>>(bcur, dstArr, swArr, rowstart, pairs);
    gather_kernel<<<N_NODES / (4 * G_NPW), 256, 0, stream>>>(x, rowstart, pairs, agg);
    gemv_kernel<<<N_NODES / GM_ROWS, 256, 0, stream>>>(agg, x, W1, b1, h, gsum, gsum2);
    mlp2_kernel<<<N_NODES / M2_ROWS, 256, 0, stream>>>(h, gsum, gsum2, gamma, beta, W2, b2);
}